// Round 19
// baseline (385.542 us; speedup 1.0000x reference)
//
#include <hip/hip_runtime.h>
#include <hip/hip_fp16.h>

#define N_NODES   50000
#define N_EDGES   800000
#define NUM_GRAPHS 256
#define IN_FEAT   64
#define REL_DIM   32
#define HID       128
#define NUM_RELS  32
#define NUM_BASES 8
#define NUM_LAYERS 2

#define NBUCK 196            // dst >> 8
#define PBLK  512            // scatter blocks
#define CHUNK 1563           // ceil(800000/512)
#define OFFN  (NBUCK * PBLK) // 100352
#define SC2_BLKS (OFFN / 256)  // 392
#define NTILES 3128          // 16-row frag tiles (>= ceil(50048/16))

typedef __attribute__((ext_vector_type(8))) _Float16 f16x8;
typedef __attribute__((ext_vector_type(4))) float f32x4;
typedef __attribute__((ext_vector_type(2))) float f32x2;

// ---------------- edge sort phase A: per-(block,bucket) histogram ----------------
__global__ void __launch_bounds__(256) k_bhist(const int* __restrict__ dst,
                                               int* __restrict__ off) {
    __shared__ int hist[NBUCK];
    int t = threadIdx.x;
    if (t < NBUCK) hist[t] = 0;
    __syncthreads();
    int base = blockIdx.x * CHUNK;
    for (int i = t; i < CHUNK; i += 256) {
        int e = base + i;
        if (e < N_EDGES) atomicAdd(&hist[dst[e] >> 8], 1);
    }
    __syncthreads();
    if (t < NBUCK) off[t * PBLK + blockIdx.x] = hist[t];
}

// ---------------- phase B: multi-block exclusive scan of off[OFFN] ----------------
__global__ void __launch_bounds__(256) k_scan2_a(int* __restrict__ off,
                                                 int* __restrict__ bsum) {
    __shared__ int s[256];
    int t = threadIdx.x;
    int idx = blockIdx.x * 256 + t;
    int v = off[idx];
    s[t] = v;
    __syncthreads();
    for (int o = 1; o < 256; o <<= 1) {
        int u = (t >= o) ? s[t - o] : 0;
        __syncthreads();
        s[t] += u;
        __syncthreads();
    }
    off[idx] = s[t] - v;                 // local exclusive
    if (t == 255) bsum[blockIdx.x] = s[255];
}

__global__ void __launch_bounds__(512) k_scan2_b(int* __restrict__ bsum,
                                                 int* __restrict__ boff) {
    __shared__ int s[512];
    int t = threadIdx.x;
    int v = (t < SC2_BLKS) ? bsum[t] : 0;
    s[t] = v;
    __syncthreads();
    for (int o = 1; o < 512; o <<= 1) {
        int u = (t >= o) ? s[t - o] : 0;
        __syncthreads();
        s[t] += u;
        __syncthreads();
    }
    if (t < SC2_BLKS) boff[t] = s[t] - v;   // exclusive
}

__global__ void __launch_bounds__(256) k_scan2_c(int* __restrict__ off,
                                                 const int* __restrict__ boff) {
    int idx = blockIdx.x * 256 + threadIdx.x;
    off[idx] += boff[blockIdx.x];
}

// ---------------- phase C: bucket-scatter (packed (dl<<21)|(src<<5)|ety) ----------------
__global__ void __launch_bounds__(256) k_bscatter(
    const int* __restrict__ src, const int* __restrict__ dst,
    const int* __restrict__ ety, const int* __restrict__ off,
    int* __restrict__ tmp) {
    __shared__ int cur[NBUCK];
    int t = threadIdx.x;
    if (t < NBUCK) cur[t] = off[t * PBLK + blockIdx.x];
    __syncthreads();
    int base = blockIdx.x * CHUNK;
    for (int i = t; i < CHUNK; i += 256) {
        int e = base + i;
        if (e < N_EDGES) {
            int d = dst[e];
            int pos = atomicAdd(&cur[d >> 8], 1);
            tmp[pos] = ((d & 255) << 21) | (src[e] << 5) | ety[e];
        }
    }
}

// ---------------- phase D: per-bucket counting sort by dst_local; emits row_start ----------------
__global__ void __launch_bounds__(256) k_bsort(
    const int* __restrict__ off, const int* __restrict__ tmp,
    int* __restrict__ edge_p, int* __restrict__ row_start) {
    int b = blockIdx.x, t = threadIdx.x;
    int eb = off[b * PBLK];
    int ee = (b == NBUCK - 1) ? N_EDGES : off[(b + 1) * PBLK];
    __shared__ int cnt[256];
    __shared__ int cur[256];
    cnt[t] = 0;
    __syncthreads();
    for (int i = eb + t; i < ee; i += 256)
        atomicAdd(&cnt[(tmp[i] >> 21) & 255], 1);
    __syncthreads();
    int v = cnt[t];
    __shared__ int s[256];
    s[t] = v;
    __syncthreads();
    for (int o = 1; o < 256; o <<= 1) {
        int u = (t >= o) ? s[t - o] : 0;
        __syncthreads();
        s[t] += u;
        __syncthreads();
    }
    int excl = s[t] - v;
    cur[t] = eb + excl;
    int node = b * 256 + t;
    if (node < N_NODES) row_start[node] = eb + excl;
    if (b == NBUCK - 1 && t == 0) row_start[N_NODES] = N_EDGES;
    __syncthreads();
    for (int i = eb + t; i < ee; i += 256) {
        int x = tmp[i];
        int pos = atomicAdd(&cur[(x >> 21) & 255], 1);
        edge_p[pos] = x & 0x1FFFFF;      // (src<<5)|ety
    }
}

// ---------------- input projection (16 nodes/block): h16 = fp16(relu([feat, er] @ W_in + b_in)) ----------------
__global__ void __launch_bounds__(128) k_input(
    const float* __restrict__ feat, const int* __restrict__ qrel,
    const float* __restrict__ rel_emb, const float* __restrict__ Wi,
    const float* __restrict__ bi, unsigned short* __restrict__ h16,
    float* __restrict__ er) {
    int n0 = blockIdx.x * 16;
    int j = threadIdx.x;
    int u = j >> 3, q = j & 7;
    __shared__ float xT[96][16];
    {
        const float4* f4 = (const float4*)(feat + (size_t)(n0 + u) * IN_FEAT);
        float4 a = f4[q], b = f4[q + 8];
        xT[4 * q + 0][u] = a.x; xT[4 * q + 1][u] = a.y;
        xT[4 * q + 2][u] = a.z; xT[4 * q + 3][u] = a.w;
        xT[32 + 4 * q + 0][u] = b.x; xT[32 + 4 * q + 1][u] = b.y;
        xT[32 + 4 * q + 2][u] = b.z; xT[32 + 4 * q + 3][u] = b.w;
        int qr = qrel[n0 + u];
        float4 e4 = ((const float4*)(rel_emb + (size_t)qr * REL_DIM))[q];
        xT[64 + 4 * q + 0][u] = e4.x; xT[64 + 4 * q + 1][u] = e4.y;
        xT[64 + 4 * q + 2][u] = e4.z; xT[64 + 4 * q + 3][u] = e4.w;
        ((float4*)(er + (size_t)(n0 + u) * REL_DIM))[q] = e4;
    }
    __syncthreads();
    float bj = bi[j];
    float acc[16];
#pragma unroll
    for (int k = 0; k < 16; k++) acc[k] = bj;
    for (int d = 0; d < 96; d++) {
        float w = Wi[d * HID + j];
        float4 x0 = *(const float4*)&xT[d][0];
        float4 x1 = *(const float4*)&xT[d][4];
        float4 x2 = *(const float4*)&xT[d][8];
        float4 x3 = *(const float4*)&xT[d][12];
        acc[0]  = fmaf(x0.x, w, acc[0]);  acc[1]  = fmaf(x0.y, w, acc[1]);
        acc[2]  = fmaf(x0.z, w, acc[2]);  acc[3]  = fmaf(x0.w, w, acc[3]);
        acc[4]  = fmaf(x1.x, w, acc[4]);  acc[5]  = fmaf(x1.y, w, acc[5]);
        acc[6]  = fmaf(x1.z, w, acc[6]);  acc[7]  = fmaf(x1.w, w, acc[7]);
        acc[8]  = fmaf(x2.x, w, acc[8]);  acc[9]  = fmaf(x2.y, w, acc[9]);
        acc[10] = fmaf(x2.z, w, acc[10]); acc[11] = fmaf(x2.w, w, acc[11]);
        acc[12] = fmaf(x3.x, w, acc[12]); acc[13] = fmaf(x3.y, w, acc[13]);
        acc[14] = fmaf(x3.z, w, acc[14]); acc[15] = fmaf(x3.w, w, acc[15]);
    }
#pragma unroll
    for (int k = 0; k < 16; k++) {
        float v = fmaxf(acc[k], 0.f);
        __half hv = __float2half(v);
        h16[(size_t)(n0 + k) * HID + j] = __builtin_bit_cast(unsigned short, hv);
    }
}

// ---------------- per-dst basis-weighted gather; G written in MFMA-FRAGMENT order ----------------
// Tile = 16 rows, 32 KB: offset = s*512 + ((row&15)+16*((k>>3)&3))*8 + (k&7),
// s = k>>5 (k < 1024). mix2 lane L holds k = b*128 + 2L, 2L+1:
// s = b*4 + (L>>4), slot qq = (L>>2)&3, j = 2*(L&3).
__global__ void __launch_bounds__(256) k_mix2(
    const unsigned short* __restrict__ h16, const float* __restrict__ comp_l,
    const int* __restrict__ row_start, const int* __restrict__ edge_p,
    unsigned short* __restrict__ Gf) {
    __shared__ f32x2 cs2[NUM_RELS * NUM_BASES];
    if (threadIdx.x < NUM_RELS * NUM_BASES) {
        float c = comp_l[threadIdx.x];
        cs2[threadIdx.x] = (f32x2){c, c};
    }
    __syncthreads();
    int wave = threadIdx.x >> 6, lane = threadIdx.x & 63;
    int n = blockIdx.x * 4 + wave;
    if (n >= N_NODES) return;
    int e0 = row_start[n], e1 = row_start[n + 1];
    f32x2 acc[NUM_BASES] = {};
    int e = e0;
    for (; e + 8 <= e1; e += 8) {
        int p0 = edge_p[e],     p1 = edge_p[e + 1], p2 = edge_p[e + 2], p3 = edge_p[e + 3];
        int p4 = edge_p[e + 4], p5 = edge_p[e + 5], p6 = edge_p[e + 6], p7 = edge_p[e + 7];
        unsigned u0 = ((const unsigned*)(h16 + (size_t)(p0 >> 5) * HID))[lane];
        unsigned u1 = ((const unsigned*)(h16 + (size_t)(p1 >> 5) * HID))[lane];
        unsigned u2 = ((const unsigned*)(h16 + (size_t)(p2 >> 5) * HID))[lane];
        unsigned u3 = ((const unsigned*)(h16 + (size_t)(p3 >> 5) * HID))[lane];
        unsigned u4 = ((const unsigned*)(h16 + (size_t)(p4 >> 5) * HID))[lane];
        unsigned u5 = ((const unsigned*)(h16 + (size_t)(p5 >> 5) * HID))[lane];
        unsigned u6 = ((const unsigned*)(h16 + (size_t)(p6 >> 5) * HID))[lane];
        unsigned u7 = ((const unsigned*)(h16 + (size_t)(p7 >> 5) * HID))[lane];
        const f32x2* c0p = &cs2[(p0 & 31) * NUM_BASES];
        const f32x2* c1p = &cs2[(p1 & 31) * NUM_BASES];
        const f32x2* c2p = &cs2[(p2 & 31) * NUM_BASES];
        const f32x2* c3p = &cs2[(p3 & 31) * NUM_BASES];
        const f32x2* c4p = &cs2[(p4 & 31) * NUM_BASES];
        const f32x2* c5p = &cs2[(p5 & 31) * NUM_BASES];
        const f32x2* c6p = &cs2[(p6 & 31) * NUM_BASES];
        const f32x2* c7p = &cs2[(p7 & 31) * NUM_BASES];
        float2 t0 = __half22float2(__builtin_bit_cast(__half2, u0));
        float2 t1 = __half22float2(__builtin_bit_cast(__half2, u1));
        float2 t2 = __half22float2(__builtin_bit_cast(__half2, u2));
        float2 t3 = __half22float2(__builtin_bit_cast(__half2, u3));
        float2 t4 = __half22float2(__builtin_bit_cast(__half2, u4));
        float2 t5 = __half22float2(__builtin_bit_cast(__half2, u5));
        float2 t6 = __half22float2(__builtin_bit_cast(__half2, u6));
        float2 t7 = __half22float2(__builtin_bit_cast(__half2, u7));
        f32x2 v0 = {t0.x, t0.y}, v1 = {t1.x, t1.y}, v2 = {t2.x, t2.y}, v3 = {t3.x, t3.y};
        f32x2 v4 = {t4.x, t4.y}, v5 = {t5.x, t5.y}, v6 = {t6.x, t6.y}, v7 = {t7.x, t7.y};
#pragma unroll
        for (int b = 0; b < NUM_BASES; b++) {
            acc[b] += c0p[b] * v0;
            acc[b] += c1p[b] * v1;
            acc[b] += c2p[b] * v2;
            acc[b] += c3p[b] * v3;
            acc[b] += c4p[b] * v4;
            acc[b] += c5p[b] * v5;
            acc[b] += c6p[b] * v6;
            acc[b] += c7p[b] * v7;
        }
    }
    for (; e < e1; e++) {
        int se = edge_p[e];
        const f32x2* cp = &cs2[(se & 31) * NUM_BASES];
        unsigned u = ((const unsigned*)(h16 + (size_t)(se >> 5) * HID))[lane];
        float2 tv = __half22float2(__builtin_bit_cast(__half2, u));
        f32x2 v = {tv.x, tv.y};
#pragma unroll
        for (int b = 0; b < NUM_BASES; b++) acc[b] += cp[b] * v;
    }
    // frag-order store
    int sgrp = lane >> 4;
    int qq = (lane >> 2) & 3;
    int jj = 2 * (lane & 3);
    unsigned short* base = Gf + (size_t)(n >> 4) * 16384
                              + ((n & 15) + 16 * qq) * 8 + jj;
#pragma unroll
    for (int b = 0; b < NUM_BASES; b++) {
        __half2 g2 = __floats2half2_rn(acc[b][0], acc[b][1]);
        *(ushort2*)(base + (size_t)(b * 4 + sgrp) * 512) =
            __builtin_bit_cast(ushort2, g2);
    }
}

// ---------------- B fragment table: f16 (hi only) of [Vl ; Wl], MFMA fragment order ----------------
__global__ void k_bfrag(const float* __restrict__ V, const float* __restrict__ W_loop,
                        unsigned short* __restrict__ Bf) {
    int idx = blockIdx.x * 256 + threadIdx.x;
    if (idx >= NUM_LAYERS * 36 * 8 * 64) return;
    int lane = idx & 63;
    int t = (idx >> 6) & 7;
    int s = (idx >> 9) % 36;
    int l = (idx >> 9) / 36;
    int col = t * 16 + (lane & 15);
    int kbase = s * 32 + (lane >> 4) * 8;
    unsigned short* o = Bf + (size_t)idx * 8;
#pragma unroll
    for (int j = 0; j < 8; j++) {
        int k = kbase + j;
        float f = (k < 1024) ? V[((size_t)l * 1024 + k) * HID + col]
                             : W_loop[((size_t)l * HID + (k - 1024)) * HID + col];
        __half hh = __float2half(f);
        o[j] = __builtin_bit_cast(unsigned short, hh);
    }
}

// ---------------- f16 MFMA GEMM, LDS-free: direct fragment loads from Gf ----------------
// out16 = fp16(relu([G | h] @ f16([Vl ; Wl]) + bl)).  M=N_NODES, K=1152, N=128.
// Block = 64 rows x 128 cols, 4 waves col-split (t = 2w, 2w+1), 4 rowgroups.
// No LDS, no barriers: per s, 4 A-frag + 2 B-frag coalesced 16B loads, 8 MFMAs.
__global__ void __launch_bounds__(256) k_gemm10(
    const unsigned short* __restrict__ Gf, const unsigned short* __restrict__ h16,
    const unsigned short* __restrict__ Bf, const float* __restrict__ bl,
    unsigned short* __restrict__ out16) {
    int lane = threadIdx.x & 63;
    int w = threadIdx.x >> 6;
    int rit = lane & 15, kg = lane >> 4;
    int r0 = blockIdx.x * 64;
    const unsigned short* ga0 = Gf + (size_t)(r0 / 16 + 0) * 16384 + lane * 8;
    const unsigned short* ga1 = Gf + (size_t)(r0 / 16 + 1) * 16384 + lane * 8;
    const unsigned short* ga2 = Gf + (size_t)(r0 / 16 + 2) * 16384 + lane * 8;
    const unsigned short* ga3 = Gf + (size_t)(r0 / 16 + 3) * 16384 + lane * 8;
    const f16x8* bb = (const f16x8*)Bf + (size_t)(2 * w) * 64 + lane;
    f32x4 acc[4][2] = {};
#pragma unroll 8
    for (int s = 0; s < 32; s++) {
        f16x8 bh0 = bb[(size_t)s * 512];
        f16x8 bh1 = bb[(size_t)s * 512 + 64];
        f16x8 a0 = *(const f16x8*)(ga0 + s * 512);
        f16x8 a1 = *(const f16x8*)(ga1 + s * 512);
        f16x8 a2 = *(const f16x8*)(ga2 + s * 512);
        f16x8 a3 = *(const f16x8*)(ga3 + s * 512);
        acc[0][0] = __builtin_amdgcn_mfma_f32_16x16x32_f16(a0, bh0, acc[0][0], 0, 0, 0);
        acc[0][1] = __builtin_amdgcn_mfma_f32_16x16x32_f16(a0, bh1, acc[0][1], 0, 0, 0);
        acc[1][0] = __builtin_amdgcn_mfma_f32_16x16x32_f16(a1, bh0, acc[1][0], 0, 0, 0);
        acc[1][1] = __builtin_amdgcn_mfma_f32_16x16x32_f16(a1, bh1, acc[1][1], 0, 0, 0);
        acc[2][0] = __builtin_amdgcn_mfma_f32_16x16x32_f16(a2, bh0, acc[2][0], 0, 0, 0);
        acc[2][1] = __builtin_amdgcn_mfma_f32_16x16x32_f16(a2, bh1, acc[2][1], 0, 0, 0);
        acc[3][0] = __builtin_amdgcn_mfma_f32_16x16x32_f16(a3, bh0, acc[3][0], 0, 0, 0);
        acc[3][1] = __builtin_amdgcn_mfma_f32_16x16x32_f16(a3, bh1, acc[3][1], 0, 0, 0);
    }
    // K tail 1024..1151 (self-loop) from h16
    {
        int s0r = r0 + 0 * 16 + rit; if (s0r >= N_NODES) s0r = N_NODES - 1;
        int s1r = r0 + 1 * 16 + rit; if (s1r >= N_NODES) s1r = N_NODES - 1;
        int s2r = r0 + 2 * 16 + rit; if (s2r >= N_NODES) s2r = N_NODES - 1;
        int s3r = r0 + 3 * 16 + rit; if (s3r >= N_NODES) s3r = N_NODES - 1;
        const unsigned short* hp0 = h16 + (size_t)s0r * HID + kg * 8;
        const unsigned short* hp1 = h16 + (size_t)s1r * HID + kg * 8;
        const unsigned short* hp2 = h16 + (size_t)s2r * HID + kg * 8;
        const unsigned short* hp3 = h16 + (size_t)s3r * HID + kg * 8;
#pragma unroll
        for (int s = 32; s < 36; s++) {
            int o = (s - 32) * 32;
            f16x8 a0 = *(const f16x8*)(hp0 + o);
            f16x8 a1 = *(const f16x8*)(hp1 + o);
            f16x8 a2 = *(const f16x8*)(hp2 + o);
            f16x8 a3 = *(const f16x8*)(hp3 + o);
            f16x8 bh0 = bb[(size_t)s * 512];
            f16x8 bh1 = bb[(size_t)s * 512 + 64];
            acc[0][0] = __builtin_amdgcn_mfma_f32_16x16x32_f16(a0, bh0, acc[0][0], 0, 0, 0);
            acc[0][1] = __builtin_amdgcn_mfma_f32_16x16x32_f16(a0, bh1, acc[0][1], 0, 0, 0);
            acc[1][0] = __builtin_amdgcn_mfma_f32_16x16x32_f16(a1, bh0, acc[1][0], 0, 0, 0);
            acc[1][1] = __builtin_amdgcn_mfma_f32_16x16x32_f16(a1, bh1, acc[1][1], 0, 0, 0);
            acc[2][0] = __builtin_amdgcn_mfma_f32_16x16x32_f16(a2, bh0, acc[2][0], 0, 0, 0);
            acc[2][1] = __builtin_amdgcn_mfma_f32_16x16x32_f16(a2, bh1, acc[2][1], 0, 0, 0);
            acc[3][0] = __builtin_amdgcn_mfma_f32_16x16x32_f16(a3, bh0, acc[3][0], 0, 0, 0);
            acc[3][1] = __builtin_amdgcn_mfma_f32_16x16x32_f16(a3, bh1, acc[3][1], 0, 0, 0);
        }
    }
    int col0 = 2 * w * 16 + rit;
    float b0 = bl[col0], b1 = bl[col0 + 16];
#pragma unroll
    for (int i = 0; i < 4; i++) {
        int rq = r0 + i * 16 + kg * 4;
#pragma unroll
        for (int q = 0; q < 4; q++) {
            int row = rq + q;
            if (row < N_NODES) {
                float v0 = fmaxf(acc[i][0][q] + b0, 0.f);
                float v1 = fmaxf(acc[i][1][q] + b1, 0.f);
                size_t o = (size_t)row * HID;
                out16[o + col0] = __builtin_bit_cast(unsigned short, __float2half(v0));
                out16[o + col0 + 16] = __builtin_bit_cast(unsigned short, __float2half(v1));
            }
        }
    }
}

// ---------------- attention scalar score per node (16 nodes/block, h16 input) ----------------
__global__ void __launch_bounds__(128) k_score(
    const unsigned short* __restrict__ h16, const float* __restrict__ er,
    const float* __restrict__ Wa, const float* __restrict__ ba,
    const float* __restrict__ wsc, const float* __restrict__ bsc,
    float* __restrict__ a) {
    int n0 = blockIdx.x * 16;
    int j = threadIdx.x;
    int u = j >> 3, q = j & 7;
    __shared__ float xT[160][16];
    {
        const uint2* h2 = (const uint2*)(h16 + (size_t)(n0 + u) * HID);
#pragma unroll
        for (int k = 0; k < 4; k++) {
            uint2 v = h2[q + 8 * k];
            float2 f01 = __half22float2(__builtin_bit_cast(__half2, v.x));
            float2 f23 = __half22float2(__builtin_bit_cast(__half2, v.y));
            xT[32 * k + 4 * q + 0][u] = f01.x; xT[32 * k + 4 * q + 1][u] = f01.y;
            xT[32 * k + 4 * q + 2][u] = f23.x; xT[32 * k + 4 * q + 3][u] = f23.y;
        }
        float4 e4 = ((const float4*)(er + (size_t)(n0 + u) * REL_DIM))[q];
        xT[128 + 4 * q + 0][u] = e4.x; xT[128 + 4 * q + 1][u] = e4.y;
        xT[128 + 4 * q + 2][u] = e4.z; xT[128 + 4 * q + 3][u] = e4.w;
    }
    __syncthreads();
    float bj = ba[j];
    float acc[16];
#pragma unroll
    for (int k = 0; k < 16; k++) acc[k] = bj;
    for (int d = 0; d < 160; d++) {
        float w = Wa[d * HID + j];
        float4 x0 = *(const float4*)&xT[d][0];
        float4 x1 = *(const float4*)&xT[d][4];
        float4 x2 = *(const float4*)&xT[d][8];
        float4 x3 = *(const float4*)&xT[d][12];
        acc[0]  = fmaf(x0.x, w, acc[0]);  acc[1]  = fmaf(x0.y, w, acc[1]);
        acc[2]  = fmaf(x0.z, w, acc[2]);  acc[3]  = fmaf(x0.w, w, acc[3]);
        acc[4]  = fmaf(x1.x, w, acc[4]);  acc[5]  = fmaf(x1.y, w, acc[5]);
        acc[6]  = fmaf(x1.z, w, acc[6]);  acc[7]  = fmaf(x1.w, w, acc[7]);
        acc[8]  = fmaf(x2.x, w, acc[8]);  acc[9]  = fmaf(x2.y, w, acc[9]);
        acc[10] = fmaf(x2.z, w, acc[10]); acc[11] = fmaf(x2.w, w, acc[11]);
        acc[12] = fmaf(x3.x, w, acc[12]); acc[13] = fmaf(x3.y, w, acc[13]);
        acc[14] = fmaf(x3.z, w, acc[14]); acc[15] = fmaf(x3.w, w, acc[15]);
    }
    __shared__ float red[16][128];
    float wj = wsc[j];
#pragma unroll
    for (int k = 0; k < 16; k++) red[k][j] = tanhf(acc[k]) * wj;
    __syncthreads();
    for (int s = 64; s > 0; s >>= 1) {
        if (j < s) {
#pragma unroll
            for (int k = 0; k < 16; k++) red[k][j] += red[k][j + s];
        }
        __syncthreads();
    }
    if (j < 16) a[n0 + j] = red[j][0] + bsc[0];
}

// ---------------- graph boundaries (graph_id is sorted) ----------------
__global__ void k_starts(const int* __restrict__ gid, int* __restrict__ starts) {
    int g = threadIdx.x;  // 0..255
    int lo = 0, hi = N_NODES;
    while (lo < hi) {
        int mid = (lo + hi) >> 1;
        if (gid[mid] < g) lo = mid + 1; else hi = mid;
    }
    starts[g] = lo;
    if (g == 0) starts[NUM_GRAPHS] = N_NODES;
}

// ---------------- segment softmax pooling + final dot (h16 input) ----------------
__global__ void __launch_bounds__(128) k_pool(
    const unsigned short* __restrict__ h16, const float* __restrict__ a,
    const int* __restrict__ starts, const float* __restrict__ wout,
    const float* __restrict__ bout, float* __restrict__ out) {
    int g = blockIdx.x, j = threadIdx.x;
    int s0 = starts[g], s1 = starts[g + 1];
    __shared__ float red[128];
    __shared__ float exb[128];
    if (s1 <= s0) { if (j == 0) out[g] = bout[0]; return; }
    float m = -3.4e38f;
    for (int i = s0 + j; i < s1; i += 128) m = fmaxf(m, a[i]);
    red[j] = m; __syncthreads();
    for (int s = 64; s > 0; s >>= 1) {
        if (j < s) red[j] = fmaxf(red[j], red[j + s]);
        __syncthreads();
    }
    m = red[0]; __syncthreads();
    float zj = 0.f, ss = 0.f;
    for (int base = s0; base < s1; base += 128) {
        int cnt = min(128, s1 - base);
        float ev = 0.f;
        if (j < cnt) ev = expf(a[base + j] - m);
        exb[j] = ev;
        ss += ev;
        __syncthreads();
        for (int k = 0; k < cnt; k++) {
            __half hv = __builtin_bit_cast(__half, h16[(size_t)(base + k) * HID + j]);
            zj = fmaf(exb[k], __half2float(hv), zj);
        }
        __syncthreads();
    }
    red[j] = ss; __syncthreads();
    for (int s = 64; s > 0; s >>= 1) {
        if (j < s) red[j] += red[j + s];
        __syncthreads();
    }
    ss = red[0]; __syncthreads();
    red[j] = (zj / ss) * wout[j]; __syncthreads();
    for (int s = 64; s > 0; s >>= 1) {
        if (j < s) red[j] += red[j + s];
        __syncthreads();
    }
    if (j == 0) out[g] = red[0] + bout[0];
}

extern "C" void kernel_launch(void* const* d_in, const int* in_sizes, int n_in,
                              void* d_out, int out_size, void* d_ws, size_t ws_size,
                              hipStream_t stream) {
    const float* feat    = (const float*)d_in[0];
    const int*   qrel    = (const int*)d_in[1];
    const int*   src     = (const int*)d_in[2];
    const int*   dst     = (const int*)d_in[3];
    const int*   ety     = (const int*)d_in[4];
    const int*   gid     = (const int*)d_in[5];
    const float* rel_emb = (const float*)d_in[6];
    const float* W_in    = (const float*)d_in[7];
    const float* b_in    = (const float*)d_in[8];
    const float* V       = (const float*)d_in[9];
    const float* comp    = (const float*)d_in[10];
    const float* W_loop  = (const float*)d_in[11];
    const float* b_loop  = (const float*)d_in[12];
    const float* W_attn  = (const float*)d_in[13];
    const float* b_attn  = (const float*)d_in[14];
    const float* w_sc    = (const float*)d_in[15];
    const float* b_sc    = (const float*)d_in[16];
    const float* w_out   = (const float*)d_in[17];
    const float* b_out   = (const float*)d_in[18];
    float* out = (float*)d_out;

    float* ws = (float*)d_ws;
    unsigned short* h16a = (unsigned short*)ws;           // 6.4M ushort
    unsigned short* h16b = h16a + (size_t)N_NODES * HID;  // 6.4M ushort
    float* er = (float*)(h16b + (size_t)N_NODES * HID);   // 1.6M f32
    float* af = er + (size_t)N_NODES * REL_DIM;           // 50000
    int* starts    = (int*)(af + N_NODES);                // 260
    int* row_start = starts + 260;                        // 50004
    int* off       = row_start + 50004;                   // 100352
    int* bsum      = off + OFFN;                          // 392
    int* boff      = bsum + SC2_BLKS;                     // 392
    int* tmp_e     = boff + SC2_BLKS;                     // 800000
    int* edge_p    = tmp_e + 800000;                      // 800000
    unsigned short* Bf = (unsigned short*)(edge_p + 800000);  // 2*36*8*64*8 ushort
    const size_t BF_USHORT = (size_t)NUM_LAYERS * 36 * 8 * 64 * 8;
    unsigned short* Gf = Bf + BF_USHORT;                  // NTILES*16384 ushort (~102 MB)

    // --- preprocessing: bucketed counting sort -> edge_p + row_start ---
    k_bhist<<<PBLK, 256, 0, stream>>>(dst, off);
    k_scan2_a<<<SC2_BLKS, 256, 0, stream>>>(off, bsum);
    k_scan2_b<<<1, 512, 0, stream>>>(bsum, boff);
    k_scan2_c<<<SC2_BLKS, 256, 0, stream>>>(off, boff);
    k_bscatter<<<PBLK, 256, 0, stream>>>(src, dst, ety, off, tmp_e);
    k_bsort<<<NBUCK, 256, 0, stream>>>(off, tmp_e, edge_p, row_start);
    k_bfrag<<<(NUM_LAYERS * 36 * 8 * 64 + 255) / 256, 256, 0, stream>>>(V, W_loop, Bf);
    k_input<<<N_NODES / 16, 128, 0, stream>>>(feat, qrel, rel_emb, W_in, b_in, h16a, er);

    unsigned short* h16cur = h16a;
    unsigned short* h16next = h16b;
    for (int l = 0; l < NUM_LAYERS; l++) {
        const float* comp_l = comp + (size_t)l * NUM_RELS * NUM_BASES;
        const unsigned short* Bfl = Bf + (size_t)l * 36 * 8 * 64 * 8;
        const float* bl = b_loop + (size_t)l * HID;
        k_mix2<<<(N_NODES + 3) / 4, 256, 0, stream>>>(h16cur, comp_l, row_start,
                                                      edge_p, Gf);
        k_gemm10<<<(N_NODES + 63) / 64, 256, 0, stream>>>(Gf, h16cur, Bfl, bl, h16next);
        unsigned short* tmp16 = h16cur; h16cur = h16next; h16next = tmp16;
    }

    k_score<<<N_NODES / 16, 128, 0, stream>>>(h16cur, er, W_attn, b_attn, w_sc, b_sc, af);
    k_starts<<<1, 256, 0, stream>>>(gid, starts);
    k_pool<<<NUM_GRAPHS, 128, 0, stream>>>(h16cur, af, starts, w_out, b_out, out);
}

// Round 20
// 311.853 us; speedup vs baseline: 1.2363x; 1.2363x over previous
//
#include <hip/hip_runtime.h>
#include <hip/hip_fp16.h>

#define N_NODES   50000
#define N_EDGES   800000
#define NUM_GRAPHS 256
#define IN_FEAT   64
#define REL_DIM   32
#define HID       128
#define NUM_RELS  32
#define NUM_BASES 8
#define NUM_LAYERS 2

#define NBUCK 196            // dst >> 8
#define PBLK  512            // scatter blocks
#define CHUNK 1563           // ceil(800000/512)
#define OFFN  (NBUCK * PBLK) // 100352
#define SC2_BLKS (OFFN / 256)  // 392

typedef __attribute__((ext_vector_type(8))) _Float16 f16x8;
typedef __attribute__((ext_vector_type(4))) float f32x4;
typedef __attribute__((ext_vector_type(2))) float f32x2;

// async 16B global -> LDS (wave-uniform LDS base + lane*16; per-lane global src)
__device__ __forceinline__ void gld_lds16(void* lds, const void* g) {
    __builtin_amdgcn_global_load_lds(
        (const __attribute__((address_space(1))) unsigned int*)g,
        (__attribute__((address_space(3))) unsigned int*)lds, 16, 0, 0);
}

// ---------------- edge sort phase A: per-(block,bucket) histogram ----------------
__global__ void __launch_bounds__(256) k_bhist(const int* __restrict__ dst,
                                               int* __restrict__ off) {
    __shared__ int hist[NBUCK];
    int t = threadIdx.x;
    if (t < NBUCK) hist[t] = 0;
    __syncthreads();
    int base = blockIdx.x * CHUNK;
    for (int i = t; i < CHUNK; i += 256) {
        int e = base + i;
        if (e < N_EDGES) atomicAdd(&hist[dst[e] >> 8], 1);
    }
    __syncthreads();
    if (t < NBUCK) off[t * PBLK + blockIdx.x] = hist[t];
}

// ---------------- phase B: multi-block exclusive scan of off[OFFN] ----------------
__global__ void __launch_bounds__(256) k_scan2_a(int* __restrict__ off,
                                                 int* __restrict__ bsum) {
    __shared__ int s[256];
    int t = threadIdx.x;
    int idx = blockIdx.x * 256 + t;
    int v = off[idx];
    s[t] = v;
    __syncthreads();
    for (int o = 1; o < 256; o <<= 1) {
        int u = (t >= o) ? s[t - o] : 0;
        __syncthreads();
        s[t] += u;
        __syncthreads();
    }
    off[idx] = s[t] - v;                 // local exclusive
    if (t == 255) bsum[blockIdx.x] = s[255];
}

__global__ void __launch_bounds__(512) k_scan2_b(int* __restrict__ bsum,
                                                 int* __restrict__ boff) {
    __shared__ int s[512];
    int t = threadIdx.x;
    int v = (t < SC2_BLKS) ? bsum[t] : 0;
    s[t] = v;
    __syncthreads();
    for (int o = 1; o < 512; o <<= 1) {
        int u = (t >= o) ? s[t - o] : 0;
        __syncthreads();
        s[t] += u;
        __syncthreads();
    }
    if (t < SC2_BLKS) boff[t] = s[t] - v;   // exclusive
}

__global__ void __launch_bounds__(256) k_scan2_c(int* __restrict__ off,
                                                 const int* __restrict__ boff) {
    int idx = blockIdx.x * 256 + threadIdx.x;
    off[idx] += boff[blockIdx.x];
}

// ---------------- phase C: bucket-scatter (packed (dl<<21)|(src<<5)|ety) ----------------
__global__ void __launch_bounds__(256) k_bscatter(
    const int* __restrict__ src, const int* __restrict__ dst,
    const int* __restrict__ ety, const int* __restrict__ off,
    int* __restrict__ tmp) {
    __shared__ int cur[NBUCK];
    int t = threadIdx.x;
    if (t < NBUCK) cur[t] = off[t * PBLK + blockIdx.x];
    __syncthreads();
    int base = blockIdx.x * CHUNK;
    for (int i = t; i < CHUNK; i += 256) {
        int e = base + i;
        if (e < N_EDGES) {
            int d = dst[e];
            int pos = atomicAdd(&cur[d >> 8], 1);
            tmp[pos] = ((d & 255) << 21) | (src[e] << 5) | ety[e];
        }
    }
}

// ---------------- phase D: per-bucket counting sort by dst_local; emits row_start ----------------
__global__ void __launch_bounds__(256) k_bsort(
    const int* __restrict__ off, const int* __restrict__ tmp,
    int* __restrict__ edge_p, int* __restrict__ row_start) {
    int b = blockIdx.x, t = threadIdx.x;
    int eb = off[b * PBLK];
    int ee = (b == NBUCK - 1) ? N_EDGES : off[(b + 1) * PBLK];
    __shared__ int cnt[256];
    __shared__ int cur[256];
    cnt[t] = 0;
    __syncthreads();
    for (int i = eb + t; i < ee; i += 256)
        atomicAdd(&cnt[(tmp[i] >> 21) & 255], 1);
    __syncthreads();
    int v = cnt[t];
    __shared__ int s[256];
    s[t] = v;
    __syncthreads();
    for (int o = 1; o < 256; o <<= 1) {
        int u = (t >= o) ? s[t - o] : 0;
        __syncthreads();
        s[t] += u;
        __syncthreads();
    }
    int excl = s[t] - v;
    cur[t] = eb + excl;
    int node = b * 256 + t;
    if (node < N_NODES) row_start[node] = eb + excl;
    if (b == NBUCK - 1 && t == 0) row_start[N_NODES] = N_EDGES;
    __syncthreads();
    for (int i = eb + t; i < ee; i += 256) {
        int x = tmp[i];
        int pos = atomicAdd(&cur[(x >> 21) & 255], 1);
        edge_p[pos] = x & 0x1FFFFF;      // (src<<5)|ety
    }
}

// ---------------- input projection (16 nodes/block): h16 = fp16(relu([feat, er] @ W_in + b_in)) ----------------
__global__ void __launch_bounds__(128) k_input(
    const float* __restrict__ feat, const int* __restrict__ qrel,
    const float* __restrict__ rel_emb, const float* __restrict__ Wi,
    const float* __restrict__ bi, unsigned short* __restrict__ h16,
    float* __restrict__ er) {
    int n0 = blockIdx.x * 16;
    int j = threadIdx.x;
    int u = j >> 3, q = j & 7;
    __shared__ float xT[96][16];
    {
        const float4* f4 = (const float4*)(feat + (size_t)(n0 + u) * IN_FEAT);
        float4 a = f4[q], b = f4[q + 8];
        xT[4 * q + 0][u] = a.x; xT[4 * q + 1][u] = a.y;
        xT[4 * q + 2][u] = a.z; xT[4 * q + 3][u] = a.w;
        xT[32 + 4 * q + 0][u] = b.x; xT[32 + 4 * q + 1][u] = b.y;
        xT[32 + 4 * q + 2][u] = b.z; xT[32 + 4 * q + 3][u] = b.w;
        int qr = qrel[n0 + u];
        float4 e4 = ((const float4*)(rel_emb + (size_t)qr * REL_DIM))[q];
        xT[64 + 4 * q + 0][u] = e4.x; xT[64 + 4 * q + 1][u] = e4.y;
        xT[64 + 4 * q + 2][u] = e4.z; xT[64 + 4 * q + 3][u] = e4.w;
        ((float4*)(er + (size_t)(n0 + u) * REL_DIM))[q] = e4;
    }
    __syncthreads();
    float bj = bi[j];
    float acc[16];
#pragma unroll
    for (int k = 0; k < 16; k++) acc[k] = bj;
    for (int d = 0; d < 96; d++) {
        float w = Wi[d * HID + j];
        float4 x0 = *(const float4*)&xT[d][0];
        float4 x1 = *(const float4*)&xT[d][4];
        float4 x2 = *(const float4*)&xT[d][8];
        float4 x3 = *(const float4*)&xT[d][12];
        acc[0]  = fmaf(x0.x, w, acc[0]);  acc[1]  = fmaf(x0.y, w, acc[1]);
        acc[2]  = fmaf(x0.z, w, acc[2]);  acc[3]  = fmaf(x0.w, w, acc[3]);
        acc[4]  = fmaf(x1.x, w, acc[4]);  acc[5]  = fmaf(x1.y, w, acc[5]);
        acc[6]  = fmaf(x1.z, w, acc[6]);  acc[7]  = fmaf(x1.w, w, acc[7]);
        acc[8]  = fmaf(x2.x, w, acc[8]);  acc[9]  = fmaf(x2.y, w, acc[9]);
        acc[10] = fmaf(x2.z, w, acc[10]); acc[11] = fmaf(x2.w, w, acc[11]);
        acc[12] = fmaf(x3.x, w, acc[12]); acc[13] = fmaf(x3.y, w, acc[13]);
        acc[14] = fmaf(x3.z, w, acc[14]); acc[15] = fmaf(x3.w, w, acc[15]);
    }
#pragma unroll
    for (int k = 0; k < 16; k++) {
        float v = fmaxf(acc[k], 0.f);
        __half hv = __float2half(v);
        h16[(size_t)(n0 + k) * HID + j] = __builtin_bit_cast(unsigned short, hv);
    }
}

// ---------------- per-dst basis-weighted gather (fp16 h), 8-deep, compiler-packed f32x2 ----------------
__global__ void __launch_bounds__(256) k_mix2(
    const unsigned short* __restrict__ h16, const float* __restrict__ comp_l,
    const int* __restrict__ row_start, const int* __restrict__ edge_p,
    unsigned short* __restrict__ Gf, int c0, int nc) {
    __shared__ f32x2 cs2[NUM_RELS * NUM_BASES];
    if (threadIdx.x < NUM_RELS * NUM_BASES) {
        float c = comp_l[threadIdx.x];
        cs2[threadIdx.x] = (f32x2){c, c};
    }
    __syncthreads();
    int wave = threadIdx.x >> 6, lane = threadIdx.x & 63;
    int n = c0 + blockIdx.x * 4 + wave;
    if (n >= c0 + nc) return;
    int e0 = row_start[n], e1 = row_start[n + 1];
    f32x2 acc[NUM_BASES] = {};
    int e = e0;
    for (; e + 8 <= e1; e += 8) {
        int p0 = edge_p[e],     p1 = edge_p[e + 1], p2 = edge_p[e + 2], p3 = edge_p[e + 3];
        int p4 = edge_p[e + 4], p5 = edge_p[e + 5], p6 = edge_p[e + 6], p7 = edge_p[e + 7];
        unsigned u0 = ((const unsigned*)(h16 + (size_t)(p0 >> 5) * HID))[lane];
        unsigned u1 = ((const unsigned*)(h16 + (size_t)(p1 >> 5) * HID))[lane];
        unsigned u2 = ((const unsigned*)(h16 + (size_t)(p2 >> 5) * HID))[lane];
        unsigned u3 = ((const unsigned*)(h16 + (size_t)(p3 >> 5) * HID))[lane];
        unsigned u4 = ((const unsigned*)(h16 + (size_t)(p4 >> 5) * HID))[lane];
        unsigned u5 = ((const unsigned*)(h16 + (size_t)(p5 >> 5) * HID))[lane];
        unsigned u6 = ((const unsigned*)(h16 + (size_t)(p6 >> 5) * HID))[lane];
        unsigned u7 = ((const unsigned*)(h16 + (size_t)(p7 >> 5) * HID))[lane];
        const f32x2* c0p = &cs2[(p0 & 31) * NUM_BASES];
        const f32x2* c1p = &cs2[(p1 & 31) * NUM_BASES];
        const f32x2* c2p = &cs2[(p2 & 31) * NUM_BASES];
        const f32x2* c3p = &cs2[(p3 & 31) * NUM_BASES];
        const f32x2* c4p = &cs2[(p4 & 31) * NUM_BASES];
        const f32x2* c5p = &cs2[(p5 & 31) * NUM_BASES];
        const f32x2* c6p = &cs2[(p6 & 31) * NUM_BASES];
        const f32x2* c7p = &cs2[(p7 & 31) * NUM_BASES];
        float2 t0 = __half22float2(__builtin_bit_cast(__half2, u0));
        float2 t1 = __half22float2(__builtin_bit_cast(__half2, u1));
        float2 t2 = __half22float2(__builtin_bit_cast(__half2, u2));
        float2 t3 = __half22float2(__builtin_bit_cast(__half2, u3));
        float2 t4 = __half22float2(__builtin_bit_cast(__half2, u4));
        float2 t5 = __half22float2(__builtin_bit_cast(__half2, u5));
        float2 t6 = __half22float2(__builtin_bit_cast(__half2, u6));
        float2 t7 = __half22float2(__builtin_bit_cast(__half2, u7));
        f32x2 v0 = {t0.x, t0.y}, v1 = {t1.x, t1.y}, v2 = {t2.x, t2.y}, v3 = {t3.x, t3.y};
        f32x2 v4 = {t4.x, t4.y}, v5 = {t5.x, t5.y}, v6 = {t6.x, t6.y}, v7 = {t7.x, t7.y};
#pragma unroll
        for (int b = 0; b < NUM_BASES; b++) {
            acc[b] += c0p[b] * v0;
            acc[b] += c1p[b] * v1;
            acc[b] += c2p[b] * v2;
            acc[b] += c3p[b] * v3;
            acc[b] += c4p[b] * v4;
            acc[b] += c5p[b] * v5;
            acc[b] += c6p[b] * v6;
            acc[b] += c7p[b] * v7;
        }
    }
    for (; e < e1; e++) {
        int se = edge_p[e];
        const f32x2* cp = &cs2[(se & 31) * NUM_BASES];
        unsigned u = ((const unsigned*)(h16 + (size_t)(se >> 5) * HID))[lane];
        float2 tv = __half22float2(__builtin_bit_cast(__half2, u));
        f32x2 v = {tv.x, tv.y};
#pragma unroll
        for (int b = 0; b < NUM_BASES; b++) acc[b] += cp[b] * v;
    }
    size_t base = (size_t)(n - c0) * 1024 + 2 * lane;
#pragma unroll
    for (int b = 0; b < NUM_BASES; b++) {
        __half2 g2 = __floats2half2_rn(acc[b][0], acc[b][1]);
        *(unsigned*)&Gf[base + b * 128] = __builtin_bit_cast(unsigned, g2);
    }
}

// ---------------- B fragment table: f16 (hi only) of [Vl ; Wl], MFMA fragment order ----------------
__global__ void k_bfrag(const float* __restrict__ V, const float* __restrict__ W_loop,
                        unsigned short* __restrict__ Bf) {
    int idx = blockIdx.x * 256 + threadIdx.x;
    if (idx >= NUM_LAYERS * 36 * 8 * 64) return;
    int lane = idx & 63;
    int t = (idx >> 6) & 7;
    int s = (idx >> 9) % 36;
    int l = (idx >> 9) / 36;
    int col = t * 16 + (lane & 15);
    int kbase = s * 32 + (lane >> 4) * 8;
    unsigned short* o = Bf + (size_t)idx * 8;
#pragma unroll
    for (int j = 0; j < 8; j++) {
        int k = kbase + j;
        float f = (k < 1024) ? V[((size_t)l * 1024 + k) * HID + col]
                             : W_loop[((size_t)l * HID + (k - 1024)) * HID + col];
        __half hh = __float2half(f);
        o[j] = __builtin_bit_cast(unsigned short, hh);
    }
}

// ---------------- f16 MFMA GEMM (BM=64, BK=128, single-B) ----------------
__global__ void __launch_bounds__(256) k_gemm9(
    const unsigned short* __restrict__ Gf, const unsigned short* __restrict__ h16,
    const unsigned short* __restrict__ Bf, const float* __restrict__ bl,
    unsigned short* __restrict__ out16, int c0, int nc) {
    __shared__ unsigned short smem[2][16][512];  // [buf][frag][1KB] = 32KB
    int lane = threadIdx.x & 63;
    int w = threadIdx.x >> 6;
    int rit = lane & 15, kg = lane >> 4;
    int r0 = blockIdx.x * 64;
    int sr0 = r0 + 0 * 16 + rit; if (sr0 >= nc) sr0 = nc - 1;
    int sr1 = r0 + 1 * 16 + rit; if (sr1 >= nc) sr1 = nc - 1;
    int sr2 = r0 + 2 * 16 + rit; if (sr2 >= nc) sr2 = nc - 1;
    int sr3 = r0 + 3 * 16 + rit; if (sr3 >= nc) sr3 = nc - 1;
    int koff = w * 32 + kg * 8;
    const unsigned short* gs0 = Gf + (size_t)sr0 * 1024 + koff;
    const unsigned short* gs1 = Gf + (size_t)sr1 * 1024 + koff;
    const unsigned short* gs2 = Gf + (size_t)sr2 * 1024 + koff;
    const unsigned short* gs3 = Gf + (size_t)sr3 * 1024 + koff;
    const f16x8* bb = (const f16x8*)Bf + (size_t)(2 * w) * 64 + lane;
    f32x4 acc[4][2] = {};

#define STAGE(BUF, STEP) {                                        \
        gld_lds16(&smem[BUF][w * 4 + 0][0], gs0 + (STEP) * 128);  \
        gld_lds16(&smem[BUF][w * 4 + 1][0], gs1 + (STEP) * 128);  \
        gld_lds16(&smem[BUF][w * 4 + 2][0], gs2 + (STEP) * 128);  \
        gld_lds16(&smem[BUF][w * 4 + 3][0], gs3 + (STEP) * 128); }
#define CSTEP(BUF, STEP) _Pragma("unroll")                                   \
    for (int s = 0; s < 4; s++) {                                            \
        const f16x8* bp = bb + (size_t)((STEP) * 4 + s) * 512;               \
        f16x8 bh0 = bp[0], bh1 = bp[64];                                     \
        _Pragma("unroll")                                                    \
        for (int i = 0; i < 4; i++) {                                        \
            f16x8 a = *(const f16x8*)&smem[BUF][s * 4 + i][lane * 8];        \
            acc[i][0] = __builtin_amdgcn_mfma_f32_16x16x32_f16(a, bh0, acc[i][0], 0, 0, 0); \
            acc[i][1] = __builtin_amdgcn_mfma_f32_16x16x32_f16(a, bh1, acc[i][1], 0, 0, 0); \
        }                                                                    \
    }

    STAGE(0, 0);
    for (int t = 0; t < 8; t++) {
        __syncthreads();
        if (t < 7) STAGE((t + 1) & 1, t + 1);
        CSTEP(t & 1, t);
    }
    {
        const unsigned short* hp0 = h16 + (size_t)(c0 + sr0) * HID + kg * 8;
        const unsigned short* hp1 = h16 + (size_t)(c0 + sr1) * HID + kg * 8;
        const unsigned short* hp2 = h16 + (size_t)(c0 + sr2) * HID + kg * 8;
        const unsigned short* hp3 = h16 + (size_t)(c0 + sr3) * HID + kg * 8;
#pragma unroll
        for (int s = 32; s < 36; s++) {
            int o = (s - 32) * 32;
            f16x8 a0 = *(const f16x8*)(hp0 + o);
            f16x8 a1 = *(const f16x8*)(hp1 + o);
            f16x8 a2 = *(const f16x8*)(hp2 + o);
            f16x8 a3 = *(const f16x8*)(hp3 + o);
            const f16x8* bp = bb + (size_t)s * 512;
            f16x8 bh0 = bp[0], bh1 = bp[64];
            acc[0][0] = __builtin_amdgcn_mfma_f32_16x16x32_f16(a0, bh0, acc[0][0], 0, 0, 0);
            acc[0][1] = __builtin_amdgcn_mfma_f32_16x16x32_f16(a0, bh1, acc[0][1], 0, 0, 0);
            acc[1][0] = __builtin_amdgcn_mfma_f32_16x16x32_f16(a1, bh0, acc[1][0], 0, 0, 0);
            acc[1][1] = __builtin_amdgcn_mfma_f32_16x16x32_f16(a1, bh1, acc[1][1], 0, 0, 0);
            acc[2][0] = __builtin_amdgcn_mfma_f32_16x16x32_f16(a2, bh0, acc[2][0], 0, 0, 0);
            acc[2][1] = __builtin_amdgcn_mfma_f32_16x16x32_f16(a2, bh1, acc[2][1], 0, 0, 0);
            acc[3][0] = __builtin_amdgcn_mfma_f32_16x16x32_f16(a3, bh0, acc[3][0], 0, 0, 0);
            acc[3][1] = __builtin_amdgcn_mfma_f32_16x16x32_f16(a3, bh1, acc[3][1], 0, 0, 0);
        }
    }
#undef STAGE
#undef CSTEP
    int col0 = 2 * w * 16 + rit;
    float b0 = bl[col0], b1 = bl[col0 + 16];
#pragma unroll
    for (int i = 0; i < 4; i++) {
        int rq = r0 + i * 16 + kg * 4;
#pragma unroll
        for (int q = 0; q < 4; q++) {
            int row = rq + q;
            if (row < nc) {
                float v0 = fmaxf(acc[i][0][q] + b0, 0.f);
                float v1 = fmaxf(acc[i][1][q] + b1, 0.f);
                size_t o = (size_t)(c0 + row) * HID;
                out16[o + col0] = __builtin_bit_cast(unsigned short, __float2half(v0));
                out16[o + col0 + 16] = __builtin_bit_cast(unsigned short, __float2half(v1));
            }
        }
    }
}

// ---------------- attention scalar score per node (16 nodes/block, h16 input) ----------------
__global__ void __launch_bounds__(128) k_score(
    const unsigned short* __restrict__ h16, const float* __restrict__ er,
    const float* __restrict__ Wa, const float* __restrict__ ba,
    const float* __restrict__ wsc, const float* __restrict__ bsc,
    float* __restrict__ a) {
    int n0 = blockIdx.x * 16;
    int j = threadIdx.x;
    int u = j >> 3, q = j & 7;
    __shared__ float xT[160][16];
    {
        const uint2* h2 = (const uint2*)(h16 + (size_t)(n0 + u) * HID);
#pragma unroll
        for (int k = 0; k < 4; k++) {
            uint2 v = h2[q + 8 * k];
            float2 f01 = __half22float2(__builtin_bit_cast(__half2, v.x));
            float2 f23 = __half22float2(__builtin_bit_cast(__half2, v.y));
            xT[32 * k + 4 * q + 0][u] = f01.x; xT[32 * k + 4 * q + 1][u] = f01.y;
            xT[32 * k + 4 * q + 2][u] = f23.x; xT[32 * k + 4 * q + 3][u] = f23.y;
        }
        float4 e4 = ((const float4*)(er + (size_t)(n0 + u) * REL_DIM))[q];
        xT[128 + 4 * q + 0][u] = e4.x; xT[128 + 4 * q + 1][u] = e4.y;
        xT[128 + 4 * q + 2][u] = e4.z; xT[128 + 4 * q + 3][u] = e4.w;
    }
    __syncthreads();
    float bj = ba[j];
    float acc[16];
#pragma unroll
    for (int k = 0; k < 16; k++) acc[k] = bj;
    for (int d = 0; d < 160; d++) {
        float w = Wa[d * HID + j];
        float4 x0 = *(const float4*)&xT[d][0];
        float4 x1 = *(const float4*)&xT[d][4];
        float4 x2 = *(const float4*)&xT[d][8];
        float4 x3 = *(const float4*)&xT[d][12];
        acc[0]  = fmaf(x0.x, w, acc[0]);  acc[1]  = fmaf(x0.y, w, acc[1]);
        acc[2]  = fmaf(x0.z, w, acc[2]);  acc[3]  = fmaf(x0.w, w, acc[3]);
        acc[4]  = fmaf(x1.x, w, acc[4]);  acc[5]  = fmaf(x1.y, w, acc[5]);
        acc[6]  = fmaf(x1.z, w, acc[6]);  acc[7]  = fmaf(x1.w, w, acc[7]);
        acc[8]  = fmaf(x2.x, w, acc[8]);  acc[9]  = fmaf(x2.y, w, acc[9]);
        acc[10] = fmaf(x2.z, w, acc[10]); acc[11] = fmaf(x2.w, w, acc[11]);
        acc[12] = fmaf(x3.x, w, acc[12]); acc[13] = fmaf(x3.y, w, acc[13]);
        acc[14] = fmaf(x3.z, w, acc[14]); acc[15] = fmaf(x3.w, w, acc[15]);
    }
    __shared__ float red[16][128];
    float wj = wsc[j];
#pragma unroll
    for (int k = 0; k < 16; k++) red[k][j] = tanhf(acc[k]) * wj;
    __syncthreads();
    for (int s = 64; s > 0; s >>= 1) {
        if (j < s) {
#pragma unroll
            for (int k = 0; k < 16; k++) red[k][j] += red[k][j + s];
        }
        __syncthreads();
    }
    if (j < 16) a[n0 + j] = red[j][0] + bsc[0];
}

// ---------------- graph boundaries (graph_id is sorted) ----------------
__global__ void k_starts(const int* __restrict__ gid, int* __restrict__ starts) {
    int g = threadIdx.x;  // 0..255
    int lo = 0, hi = N_NODES;
    while (lo < hi) {
        int mid = (lo + hi) >> 1;
        if (gid[mid] < g) lo = mid + 1; else hi = mid;
    }
    starts[g] = lo;
    if (g == 0) starts[NUM_GRAPHS] = N_NODES;
}

// ---------------- segment softmax pooling + final dot (h16 input) ----------------
__global__ void __launch_bounds__(128) k_pool(
    const unsigned short* __restrict__ h16, const float* __restrict__ a,
    const int* __restrict__ starts, const float* __restrict__ wout,
    const float* __restrict__ bout, float* __restrict__ out) {
    int g = blockIdx.x, j = threadIdx.x;
    int s0 = starts[g], s1 = starts[g + 1];
    __shared__ float red[128];
    __shared__ float exb[128];
    if (s1 <= s0) { if (j == 0) out[g] = bout[0]; return; }
    float m = -3.4e38f;
    for (int i = s0 + j; i < s1; i += 128) m = fmaxf(m, a[i]);
    red[j] = m; __syncthreads();
    for (int s = 64; s > 0; s >>= 1) {
        if (j < s) red[j] = fmaxf(red[j], red[j + s]);
        __syncthreads();
    }
    m = red[0]; __syncthreads();
    float zj = 0.f, ss = 0.f;
    for (int base = s0; base < s1; base += 128) {
        int cnt = min(128, s1 - base);
        float ev = 0.f;
        if (j < cnt) ev = expf(a[base + j] - m);
        exb[j] = ev;
        ss += ev;
        __syncthreads();
        for (int k = 0; k < cnt; k++) {
            __half hv = __builtin_bit_cast(__half, h16[(size_t)(base + k) * HID + j]);
            zj = fmaf(exb[k], __half2float(hv), zj);
        }
        __syncthreads();
    }
    red[j] = ss; __syncthreads();
    for (int s = 64; s > 0; s >>= 1) {
        if (j < s) red[j] += red[j + s];
        __syncthreads();
    }
    ss = red[0]; __syncthreads();
    red[j] = (zj / ss) * wout[j]; __syncthreads();
    for (int s = 64; s > 0; s >>= 1) {
        if (j < s) red[j] += red[j + s];
        __syncthreads();
    }
    if (j == 0) out[g] = red[0] + bout[0];
}

extern "C" void kernel_launch(void* const* d_in, const int* in_sizes, int n_in,
                              void* d_out, int out_size, void* d_ws, size_t ws_size,
                              hipStream_t stream) {
    const float* feat    = (const float*)d_in[0];
    const int*   qrel    = (const int*)d_in[1];
    const int*   src     = (const int*)d_in[2];
    const int*   dst     = (const int*)d_in[3];
    const int*   ety     = (const int*)d_in[4];
    const int*   gid     = (const int*)d_in[5];
    const float* rel_emb = (const float*)d_in[6];
    const float* W_in    = (const float*)d_in[7];
    const float* b_in    = (const float*)d_in[8];
    const float* V       = (const float*)d_in[9];
    const float* comp    = (const float*)d_in[10];
    const float* W_loop  = (const float*)d_in[11];
    const float* b_loop  = (const float*)d_in[12];
    const float* W_attn  = (const float*)d_in[13];
    const float* b_attn  = (const float*)d_in[14];
    const float* w_sc    = (const float*)d_in[15];
    const float* b_sc    = (const float*)d_in[16];
    const float* w_out   = (const float*)d_in[17];
    const float* b_out   = (const float*)d_in[18];
    float* out = (float*)d_out;

    float* ws = (float*)d_ws;
    unsigned short* h16a = (unsigned short*)ws;           // 6.4M ushort
    unsigned short* h16b = h16a + (size_t)N_NODES * HID;  // 6.4M ushort
    float* er = (float*)(h16b + (size_t)N_NODES * HID);   // 1.6M f32
    float* af = er + (size_t)N_NODES * REL_DIM;           // 50000
    int* starts    = (int*)(af + N_NODES);                // 260
    int* row_start = starts + 260;                        // 50004
    int* off       = row_start + 50004;                   // 100352
    int* bsum      = off + OFFN;                          // 392
    int* boff      = bsum + SC2_BLKS;                     // 392
    int* tmp_e     = boff + SC2_BLKS;                     // 800000
    int* edge_p    = tmp_e + 800000;                      // 800000
    unsigned short* Bf = (unsigned short*)(edge_p + 800000);  // 2*36*8*64*8 ushort
    const size_t BF_USHORT = (size_t)NUM_LAYERS * 36 * 8 * 64 * 8;
    unsigned short* Gf = Bf + BF_USHORT;

    size_t used_floats = (size_t)((float*)Gf - ws);
    size_t total_floats = ws_size / sizeof(float);
    size_t avail = (total_floats > used_floats) ? (total_floats - used_floats) : 0;
    long long NC = (long long)(avail / 512);   // 1024 fp16 per row = 512 floats
    NC = (NC / 64) * 64;
    if (NC > 50048) NC = 50048;
    if (NC < 64) NC = 64;

    // --- preprocessing: bucketed counting sort -> edge_p + row_start ---
    k_bhist<<<PBLK, 256, 0, stream>>>(dst, off);
    k_scan2_a<<<SC2_BLKS, 256, 0, stream>>>(off, bsum);
    k_scan2_b<<<1, 512, 0, stream>>>(bsum, boff);
    k_scan2_c<<<SC2_BLKS, 256, 0, stream>>>(off, boff);
    k_bscatter<<<PBLK, 256, 0, stream>>>(src, dst, ety, off, tmp_e);
    k_bsort<<<NBUCK, 256, 0, stream>>>(off, tmp_e, edge_p, row_start);
    k_bfrag<<<(NUM_LAYERS * 36 * 8 * 64 + 255) / 256, 256, 0, stream>>>(V, W_loop, Bf);
    k_input<<<N_NODES / 16, 128, 0, stream>>>(feat, qrel, rel_emb, W_in, b_in, h16a, er);

    unsigned short* h16cur = h16a;
    unsigned short* h16next = h16b;
    for (int l = 0; l < NUM_LAYERS; l++) {
        const float* comp_l = comp + (size_t)l * NUM_RELS * NUM_BASES;
        const unsigned short* Bfl = Bf + (size_t)l * 36 * 8 * 64 * 8;
        const float* bl = b_loop + (size_t)l * HID;
        for (int c0 = 0; c0 < N_NODES; c0 += (int)NC) {
            int nc = (int)((N_NODES - c0 < NC) ? (N_NODES - c0) : NC);
            k_mix2<<<(nc + 3) / 4, 256, 0, stream>>>(h16cur, comp_l, row_start, edge_p,
                                                     Gf, c0, nc);
            k_gemm9<<<(nc + 63) / 64, 256, 0, stream>>>(Gf, h16cur, Bfl, bl,
                                                        h16next, c0, nc);
        }
        unsigned short* tmp16 = h16cur; h16cur = h16next; h16next = tmp16;
    }

    k_score<<<N_NODES / 16, 128, 0, stream>>>(h16cur, er, W_attn, b_attn, w_sc, b_sc, af);
    k_starts<<<1, 256, 0, stream>>>(gid, starts);
    k_pool<<<NUM_GRAPHS, 128, 0, stream>>>(h16cur, af, starts, w_out, b_out, out);
}

// Round 21
// 281.238 us; speedup vs baseline: 1.3709x; 1.1089x over previous
//
#include <hip/hip_runtime.h>
#include <hip/hip_fp16.h>

#define N_NODES   50000
#define N_EDGES   800000
#define NUM_GRAPHS 256
#define IN_FEAT   64
#define REL_DIM   32
#define HID       128
#define NUM_RELS  32
#define NUM_BASES 8
#define NUM_LAYERS 2

#define NBUCK 196            // dst >> 8
#define PBLK  512            // scatter blocks
#define CHUNK 1563           // ceil(800000/512)
#define OFFN  (NBUCK * PBLK) // 100352
#define SC2_BLKS (OFFN / 256)  // 392

typedef __attribute__((ext_vector_type(8))) _Float16 f16x8;
typedef __attribute__((ext_vector_type(4))) float f32x4;
typedef __attribute__((ext_vector_type(2))) float f32x2;

// async 16B global -> LDS (wave-uniform LDS base + lane*16; per-lane global src)
__device__ __forceinline__ void gld_lds16(void* lds, const void* g) {
    __builtin_amdgcn_global_load_lds(
        (const __attribute__((address_space(1))) unsigned int*)g,
        (__attribute__((address_space(3))) unsigned int*)lds, 16, 0, 0);
}

// ---------------- edge sort phase A: per-(block,bucket) histogram ----------------
__global__ void __launch_bounds__(256) k_bhist(const int* __restrict__ dst,
                                               int* __restrict__ off) {
    __shared__ int hist[NBUCK];
    int t = threadIdx.x;
    if (t < NBUCK) hist[t] = 0;
    __syncthreads();
    int base = blockIdx.x * CHUNK;
    for (int i = t; i < CHUNK; i += 256) {
        int e = base + i;
        if (e < N_EDGES) atomicAdd(&hist[dst[e] >> 8], 1);
    }
    __syncthreads();
    if (t < NBUCK) off[t * PBLK + blockIdx.x] = hist[t];
}

// ---------------- phase B: multi-block exclusive scan of off[OFFN] ----------------
__global__ void __launch_bounds__(256) k_scan2_a(int* __restrict__ off,
                                                 int* __restrict__ bsum) {
    __shared__ int s[256];
    int t = threadIdx.x;
    int idx = blockIdx.x * 256 + t;
    int v = off[idx];
    s[t] = v;
    __syncthreads();
    for (int o = 1; o < 256; o <<= 1) {
        int u = (t >= o) ? s[t - o] : 0;
        __syncthreads();
        s[t] += u;
        __syncthreads();
    }
    off[idx] = s[t] - v;                 // local exclusive
    if (t == 255) bsum[blockIdx.x] = s[255];
}

__global__ void __launch_bounds__(512) k_scan2_b(int* __restrict__ bsum,
                                                 int* __restrict__ boff) {
    __shared__ int s[512];
    int t = threadIdx.x;
    int v = (t < SC2_BLKS) ? bsum[t] : 0;
    s[t] = v;
    __syncthreads();
    for (int o = 1; o < 512; o <<= 1) {
        int u = (t >= o) ? s[t - o] : 0;
        __syncthreads();
        s[t] += u;
        __syncthreads();
    }
    if (t < SC2_BLKS) boff[t] = s[t] - v;   // exclusive
}

__global__ void __launch_bounds__(256) k_scan2_c(int* __restrict__ off,
                                                 const int* __restrict__ boff) {
    int idx = blockIdx.x * 256 + threadIdx.x;
    off[idx] += boff[blockIdx.x];
}

// ---------------- phase C: bucket-scatter (packed (dl<<21)|(src<<5)|ety) ----------------
__global__ void __launch_bounds__(256) k_bscatter(
    const int* __restrict__ src, const int* __restrict__ dst,
    const int* __restrict__ ety, const int* __restrict__ off,
    int* __restrict__ tmp) {
    __shared__ int cur[NBUCK];
    int t = threadIdx.x;
    if (t < NBUCK) cur[t] = off[t * PBLK + blockIdx.x];
    __syncthreads();
    int base = blockIdx.x * CHUNK;
    for (int i = t; i < CHUNK; i += 256) {
        int e = base + i;
        if (e < N_EDGES) {
            int d = dst[e];
            int pos = atomicAdd(&cur[d >> 8], 1);
            tmp[pos] = ((d & 255) << 21) | (src[e] << 5) | ety[e];
        }
    }
}

// ---------------- phase D: per-bucket counting sort by dst_local; emits row_start ----------------
__global__ void __launch_bounds__(256) k_bsort(
    const int* __restrict__ off, const int* __restrict__ tmp,
    int* __restrict__ edge_p, int* __restrict__ row_start) {
    int b = blockIdx.x, t = threadIdx.x;
    int eb = off[b * PBLK];
    int ee = (b == NBUCK - 1) ? N_EDGES : off[(b + 1) * PBLK];
    __shared__ int cnt[256];
    __shared__ int cur[256];
    cnt[t] = 0;
    __syncthreads();
    for (int i = eb + t; i < ee; i += 256)
        atomicAdd(&cnt[(tmp[i] >> 21) & 255], 1);
    __syncthreads();
    int v = cnt[t];
    __shared__ int s[256];
    s[t] = v;
    __syncthreads();
    for (int o = 1; o < 256; o <<= 1) {
        int u = (t >= o) ? s[t - o] : 0;
        __syncthreads();
        s[t] += u;
        __syncthreads();
    }
    int excl = s[t] - v;
    cur[t] = eb + excl;
    int node = b * 256 + t;
    if (node < N_NODES) row_start[node] = eb + excl;
    if (b == NBUCK - 1 && t == 0) row_start[N_NODES] = N_EDGES;
    __syncthreads();
    for (int i = eb + t; i < ee; i += 256) {
        int x = tmp[i];
        int pos = atomicAdd(&cur[(x >> 21) & 255], 1);
        edge_p[pos] = x & 0x1FFFFF;      // (src<<5)|ety
    }
}

// ---------------- input projection (16 nodes/block): h16 = fp16(relu([feat, er] @ W_in + b_in)) ----------------
__global__ void __launch_bounds__(128) k_input(
    const float* __restrict__ feat, const int* __restrict__ qrel,
    const float* __restrict__ rel_emb, const float* __restrict__ Wi,
    const float* __restrict__ bi, unsigned short* __restrict__ h16,
    unsigned short* __restrict__ er16) {
    int n0 = blockIdx.x * 16;
    int j = threadIdx.x;
    int u = j >> 3, q = j & 7;
    __shared__ float xT[96][16];
    {
        const float4* f4 = (const float4*)(feat + (size_t)(n0 + u) * IN_FEAT);
        float4 a = f4[q], b = f4[q + 8];
        xT[4 * q + 0][u] = a.x; xT[4 * q + 1][u] = a.y;
        xT[4 * q + 2][u] = a.z; xT[4 * q + 3][u] = a.w;
        xT[32 + 4 * q + 0][u] = b.x; xT[32 + 4 * q + 1][u] = b.y;
        xT[32 + 4 * q + 2][u] = b.z; xT[32 + 4 * q + 3][u] = b.w;
        int qr = qrel[n0 + u];
        float4 e4 = ((const float4*)(rel_emb + (size_t)qr * REL_DIM))[q];
        xT[64 + 4 * q + 0][u] = e4.x; xT[64 + 4 * q + 1][u] = e4.y;
        xT[64 + 4 * q + 2][u] = e4.z; xT[64 + 4 * q + 3][u] = e4.w;
        __half2 e01 = __floats2half2_rn(e4.x, e4.y);
        __half2 e23 = __floats2half2_rn(e4.z, e4.w);
        *(unsigned*)&er16[(size_t)(n0 + u) * REL_DIM + 4 * q] =
            __builtin_bit_cast(unsigned, e01);
        *(unsigned*)&er16[(size_t)(n0 + u) * REL_DIM + 4 * q + 2] =
            __builtin_bit_cast(unsigned, e23);
    }
    __syncthreads();
    float bj = bi[j];
    float acc[16];
#pragma unroll
    for (int k = 0; k < 16; k++) acc[k] = bj;
    for (int d = 0; d < 96; d++) {
        float w = Wi[d * HID + j];
        float4 x0 = *(const float4*)&xT[d][0];
        float4 x1 = *(const float4*)&xT[d][4];
        float4 x2 = *(const float4*)&xT[d][8];
        float4 x3 = *(const float4*)&xT[d][12];
        acc[0]  = fmaf(x0.x, w, acc[0]);  acc[1]  = fmaf(x0.y, w, acc[1]);
        acc[2]  = fmaf(x0.z, w, acc[2]);  acc[3]  = fmaf(x0.w, w, acc[3]);
        acc[4]  = fmaf(x1.x, w, acc[4]);  acc[5]  = fmaf(x1.y, w, acc[5]);
        acc[6]  = fmaf(x1.z, w, acc[6]);  acc[7]  = fmaf(x1.w, w, acc[7]);
        acc[8]  = fmaf(x2.x, w, acc[8]);  acc[9]  = fmaf(x2.y, w, acc[9]);
        acc[10] = fmaf(x2.z, w, acc[10]); acc[11] = fmaf(x2.w, w, acc[11]);
        acc[12] = fmaf(x3.x, w, acc[12]); acc[13] = fmaf(x3.y, w, acc[13]);
        acc[14] = fmaf(x3.z, w, acc[14]); acc[15] = fmaf(x3.w, w, acc[15]);
    }
#pragma unroll
    for (int k = 0; k < 16; k++) {
        float v = fmaxf(acc[k], 0.f);
        __half hv = __float2half(v);
        h16[(size_t)(n0 + k) * HID + j] = __builtin_bit_cast(unsigned short, hv);
    }
}

// ---------------- per-dst basis-weighted gather (fp16 h), 8-deep, compiler-packed f32x2 ----------------
__global__ void __launch_bounds__(256) k_mix2(
    const unsigned short* __restrict__ h16, const float* __restrict__ comp_l,
    const int* __restrict__ row_start, const int* __restrict__ edge_p,
    unsigned short* __restrict__ Gf, int c0, int nc) {
    __shared__ f32x2 cs2[NUM_RELS * NUM_BASES];
    if (threadIdx.x < NUM_RELS * NUM_BASES) {
        float c = comp_l[threadIdx.x];
        cs2[threadIdx.x] = (f32x2){c, c};
    }
    __syncthreads();
    int wave = threadIdx.x >> 6, lane = threadIdx.x & 63;
    int n = c0 + blockIdx.x * 4 + wave;
    if (n >= c0 + nc) return;
    int e0 = row_start[n], e1 = row_start[n + 1];
    f32x2 acc[NUM_BASES] = {};
    int e = e0;
    for (; e + 8 <= e1; e += 8) {
        int p0 = edge_p[e],     p1 = edge_p[e + 1], p2 = edge_p[e + 2], p3 = edge_p[e + 3];
        int p4 = edge_p[e + 4], p5 = edge_p[e + 5], p6 = edge_p[e + 6], p7 = edge_p[e + 7];
        unsigned u0 = ((const unsigned*)(h16 + (size_t)(p0 >> 5) * HID))[lane];
        unsigned u1 = ((const unsigned*)(h16 + (size_t)(p1 >> 5) * HID))[lane];
        unsigned u2 = ((const unsigned*)(h16 + (size_t)(p2 >> 5) * HID))[lane];
        unsigned u3 = ((const unsigned*)(h16 + (size_t)(p3 >> 5) * HID))[lane];
        unsigned u4 = ((const unsigned*)(h16 + (size_t)(p4 >> 5) * HID))[lane];
        unsigned u5 = ((const unsigned*)(h16 + (size_t)(p5 >> 5) * HID))[lane];
        unsigned u6 = ((const unsigned*)(h16 + (size_t)(p6 >> 5) * HID))[lane];
        unsigned u7 = ((const unsigned*)(h16 + (size_t)(p7 >> 5) * HID))[lane];
        const f32x2* c0p = &cs2[(p0 & 31) * NUM_BASES];
        const f32x2* c1p = &cs2[(p1 & 31) * NUM_BASES];
        const f32x2* c2p = &cs2[(p2 & 31) * NUM_BASES];
        const f32x2* c3p = &cs2[(p3 & 31) * NUM_BASES];
        const f32x2* c4p = &cs2[(p4 & 31) * NUM_BASES];
        const f32x2* c5p = &cs2[(p5 & 31) * NUM_BASES];
        const f32x2* c6p = &cs2[(p6 & 31) * NUM_BASES];
        const f32x2* c7p = &cs2[(p7 & 31) * NUM_BASES];
        float2 t0 = __half22float2(__builtin_bit_cast(__half2, u0));
        float2 t1 = __half22float2(__builtin_bit_cast(__half2, u1));
        float2 t2 = __half22float2(__builtin_bit_cast(__half2, u2));
        float2 t3 = __half22float2(__builtin_bit_cast(__half2, u3));
        float2 t4 = __half22float2(__builtin_bit_cast(__half2, u4));
        float2 t5 = __half22float2(__builtin_bit_cast(__half2, u5));
        float2 t6 = __half22float2(__builtin_bit_cast(__half2, u6));
        float2 t7 = __half22float2(__builtin_bit_cast(__half2, u7));
        f32x2 v0 = {t0.x, t0.y}, v1 = {t1.x, t1.y}, v2 = {t2.x, t2.y}, v3 = {t3.x, t3.y};
        f32x2 v4 = {t4.x, t4.y}, v5 = {t5.x, t5.y}, v6 = {t6.x, t6.y}, v7 = {t7.x, t7.y};
#pragma unroll
        for (int b = 0; b < NUM_BASES; b++) {
            acc[b] += c0p[b] * v0;
            acc[b] += c1p[b] * v1;
            acc[b] += c2p[b] * v2;
            acc[b] += c3p[b] * v3;
            acc[b] += c4p[b] * v4;
            acc[b] += c5p[b] * v5;
            acc[b] += c6p[b] * v6;
            acc[b] += c7p[b] * v7;
        }
    }
    for (; e < e1; e++) {
        int se = edge_p[e];
        const f32x2* cp = &cs2[(se & 31) * NUM_BASES];
        unsigned u = ((const unsigned*)(h16 + (size_t)(se >> 5) * HID))[lane];
        float2 tv = __half22float2(__builtin_bit_cast(__half2, u));
        f32x2 v = {tv.x, tv.y};
#pragma unroll
        for (int b = 0; b < NUM_BASES; b++) acc[b] += cp[b] * v;
    }
    size_t base = (size_t)(n - c0) * 1024 + 2 * lane;
#pragma unroll
    for (int b = 0; b < NUM_BASES; b++) {
        __half2 g2 = __floats2half2_rn(acc[b][0], acc[b][1]);
        *(unsigned*)&Gf[base + b * 128] = __builtin_bit_cast(unsigned, g2);
    }
}

// ---------------- B fragment table: f16 (hi only) of [Vl ; Wl], MFMA fragment order ----------------
__global__ void k_bfrag(const float* __restrict__ V, const float* __restrict__ W_loop,
                        unsigned short* __restrict__ Bf) {
    int idx = blockIdx.x * 256 + threadIdx.x;
    if (idx >= NUM_LAYERS * 36 * 8 * 64) return;
    int lane = idx & 63;
    int t = (idx >> 6) & 7;
    int s = (idx >> 9) % 36;
    int l = (idx >> 9) / 36;
    int col = t * 16 + (lane & 15);
    int kbase = s * 32 + (lane >> 4) * 8;
    unsigned short* o = Bf + (size_t)idx * 8;
#pragma unroll
    for (int j = 0; j < 8; j++) {
        int k = kbase + j;
        float f = (k < 1024) ? V[((size_t)l * 1024 + k) * HID + col]
                             : W_loop[((size_t)l * HID + (k - 1024)) * HID + col];
        __half hh = __float2half(f);
        o[j] = __builtin_bit_cast(unsigned short, hh);
    }
}

// ---------------- generic frag table for a [S*32][128] f32 matrix (hi f16) ----------------
__global__ void k_bfragw(const float* __restrict__ W, unsigned short* __restrict__ out,
                         int S) {
    int idx = blockIdx.x * 256 + threadIdx.x;
    if (idx >= S * 8 * 64) return;
    int lane = idx & 63;
    int t = (idx >> 6) & 7;
    int s = idx >> 9;
    int col = t * 16 + (lane & 15);
    int kbase = s * 32 + (lane >> 4) * 8;
    unsigned short* o = out + (size_t)idx * 8;
#pragma unroll
    for (int j = 0; j < 8; j++) {
        __half hh = __float2half(W[(size_t)(kbase + j) * HID + col]);
        o[j] = __builtin_bit_cast(unsigned short, hh);
    }
}

// ---------------- f16 MFMA GEMM (BM=64, BK=128, single-B) ----------------
__global__ void __launch_bounds__(256) k_gemm9(
    const unsigned short* __restrict__ Gf, const unsigned short* __restrict__ h16,
    const unsigned short* __restrict__ Bf, const float* __restrict__ bl,
    unsigned short* __restrict__ out16, int c0, int nc) {
    __shared__ unsigned short smem[2][16][512];  // [buf][frag][1KB] = 32KB
    int lane = threadIdx.x & 63;
    int w = threadIdx.x >> 6;
    int rit = lane & 15, kg = lane >> 4;
    int r0 = blockIdx.x * 64;
    int sr0 = r0 + 0 * 16 + rit; if (sr0 >= nc) sr0 = nc - 1;
    int sr1 = r0 + 1 * 16 + rit; if (sr1 >= nc) sr1 = nc - 1;
    int sr2 = r0 + 2 * 16 + rit; if (sr2 >= nc) sr2 = nc - 1;
    int sr3 = r0 + 3 * 16 + rit; if (sr3 >= nc) sr3 = nc - 1;
    int koff = w * 32 + kg * 8;
    const unsigned short* gs0 = Gf + (size_t)sr0 * 1024 + koff;
    const unsigned short* gs1 = Gf + (size_t)sr1 * 1024 + koff;
    const unsigned short* gs2 = Gf + (size_t)sr2 * 1024 + koff;
    const unsigned short* gs3 = Gf + (size_t)sr3 * 1024 + koff;
    const f16x8* bb = (const f16x8*)Bf + (size_t)(2 * w) * 64 + lane;
    f32x4 acc[4][2] = {};

#define STAGE(BUF, STEP) {                                        \
        gld_lds16(&smem[BUF][w * 4 + 0][0], gs0 + (STEP) * 128);  \
        gld_lds16(&smem[BUF][w * 4 + 1][0], gs1 + (STEP) * 128);  \
        gld_lds16(&smem[BUF][w * 4 + 2][0], gs2 + (STEP) * 128);  \
        gld_lds16(&smem[BUF][w * 4 + 3][0], gs3 + (STEP) * 128); }
#define CSTEP(BUF, STEP) _Pragma("unroll")                                   \
    for (int s = 0; s < 4; s++) {                                            \
        const f16x8* bp = bb + (size_t)((STEP) * 4 + s) * 512;               \
        f16x8 bh0 = bp[0], bh1 = bp[64];                                     \
        _Pragma("unroll")                                                    \
        for (int i = 0; i < 4; i++) {                                        \
            f16x8 a = *(const f16x8*)&smem[BUF][s * 4 + i][lane * 8];        \
            acc[i][0] = __builtin_amdgcn_mfma_f32_16x16x32_f16(a, bh0, acc[i][0], 0, 0, 0); \
            acc[i][1] = __builtin_amdgcn_mfma_f32_16x16x32_f16(a, bh1, acc[i][1], 0, 0, 0); \
        }                                                                    \
    }

    STAGE(0, 0);
    for (int t = 0; t < 8; t++) {
        __syncthreads();
        if (t < 7) STAGE((t + 1) & 1, t + 1);
        CSTEP(t & 1, t);
    }
    {
        const unsigned short* hp0 = h16 + (size_t)(c0 + sr0) * HID + kg * 8;
        const unsigned short* hp1 = h16 + (size_t)(c0 + sr1) * HID + kg * 8;
        const unsigned short* hp2 = h16 + (size_t)(c0 + sr2) * HID + kg * 8;
        const unsigned short* hp3 = h16 + (size_t)(c0 + sr3) * HID + kg * 8;
#pragma unroll
        for (int s = 32; s < 36; s++) {
            int o = (s - 32) * 32;
            f16x8 a0 = *(const f16x8*)(hp0 + o);
            f16x8 a1 = *(const f16x8*)(hp1 + o);
            f16x8 a2 = *(const f16x8*)(hp2 + o);
            f16x8 a3 = *(const f16x8*)(hp3 + o);
            const f16x8* bp = bb + (size_t)s * 512;
            f16x8 bh0 = bp[0], bh1 = bp[64];
            acc[0][0] = __builtin_amdgcn_mfma_f32_16x16x32_f16(a0, bh0, acc[0][0], 0, 0, 0);
            acc[0][1] = __builtin_amdgcn_mfma_f32_16x16x32_f16(a0, bh1, acc[0][1], 0, 0, 0);
            acc[1][0] = __builtin_amdgcn_mfma_f32_16x16x32_f16(a1, bh0, acc[1][0], 0, 0, 0);
            acc[1][1] = __builtin_amdgcn_mfma_f32_16x16x32_f16(a1, bh1, acc[1][1], 0, 0, 0);
            acc[2][0] = __builtin_amdgcn_mfma_f32_16x16x32_f16(a2, bh0, acc[2][0], 0, 0, 0);
            acc[2][1] = __builtin_amdgcn_mfma_f32_16x16x32_f16(a2, bh1, acc[2][1], 0, 0, 0);
            acc[3][0] = __builtin_amdgcn_mfma_f32_16x16x32_f16(a3, bh0, acc[3][0], 0, 0, 0);
            acc[3][1] = __builtin_amdgcn_mfma_f32_16x16x32_f16(a3, bh1, acc[3][1], 0, 0, 0);
        }
    }
#undef STAGE
#undef CSTEP
    int col0 = 2 * w * 16 + rit;
    float b0 = bl[col0], b1 = bl[col0 + 16];
#pragma unroll
    for (int i = 0; i < 4; i++) {
        int rq = r0 + i * 16 + kg * 4;
#pragma unroll
        for (int q = 0; q < 4; q++) {
            int row = rq + q;
            if (row < nc) {
                float v0 = fmaxf(acc[i][0][q] + b0, 0.f);
                float v1 = fmaxf(acc[i][1][q] + b1, 0.f);
                size_t o = (size_t)(c0 + row) * HID;
                out16[o + col0] = __builtin_bit_cast(unsigned short, __float2half(v0));
                out16[o + col0 + 16] = __builtin_bit_cast(unsigned short, __float2half(v1));
            }
        }
    }
}

// ---------------- MFMA attention score: a = tanh([h16|er16]@Wa + ba)@wsc + bsc ----------------
// Block 256 = 4 waves; wave handles 16 rows. K=160 (5 s-tiles). No LDS.
// C layout: col = lane&15, row = (lane>>4)*4 + q; col-sum via shfl_xor over 16 lanes.
__global__ void __launch_bounds__(256) k_score2(
    const unsigned short* __restrict__ h16, const unsigned short* __restrict__ er16,
    const unsigned short* __restrict__ Waf, const float* __restrict__ ba,
    const float* __restrict__ wsc, const float* __restrict__ bsc,
    float* __restrict__ a) {
    int lane = threadIdx.x & 63, w = threadIdx.x >> 6;
    int r0 = blockIdx.x * 64 + w * 16;
    int rit = lane & 15, kg = lane >> 4;
    int row = r0 + rit; if (row >= N_NODES) row = N_NODES - 1;
    const f16x8* bb = (const f16x8*)Waf;
    f32x4 acc[8] = {};
#pragma unroll
    for (int s = 0; s < 5; s++) {
        f16x8 a8;
        if (s < 4) a8 = *(const f16x8*)(h16 + (size_t)row * HID + s * 32 + kg * 8);
        else       a8 = *(const f16x8*)(er16 + (size_t)row * REL_DIM + kg * 8);
#pragma unroll
        for (int t = 0; t < 8; t++)
            acc[t] = __builtin_amdgcn_mfma_f32_16x16x32_f16(
                a8, bb[(size_t)(s * 8 + t) * 64 + lane], acc[t], 0, 0, 0);
    }
    float p0 = 0.f, p1 = 0.f, p2 = 0.f, p3 = 0.f;
#pragma unroll
    for (int t = 0; t < 8; t++) {
        int col = t * 16 + rit;
        float bc = ba[col];
        float ws = wsc[col];
        p0 += tanhf(acc[t][0] + bc) * ws;
        p1 += tanhf(acc[t][1] + bc) * ws;
        p2 += tanhf(acc[t][2] + bc) * ws;
        p3 += tanhf(acc[t][3] + bc) * ws;
    }
#pragma unroll
    for (int m = 1; m < 16; m <<= 1) {
        p0 += __shfl_xor(p0, m, 64);
        p1 += __shfl_xor(p1, m, 64);
        p2 += __shfl_xor(p2, m, 64);
        p3 += __shfl_xor(p3, m, 64);
    }
    if (rit == 0) {
        float bs = bsc[0];
        int rr = r0 + kg * 4;
        if (rr + 0 < N_NODES) a[rr + 0] = p0 + bs;
        if (rr + 1 < N_NODES) a[rr + 1] = p1 + bs;
        if (rr + 2 < N_NODES) a[rr + 2] = p2 + bs;
        if (rr + 3 < N_NODES) a[rr + 3] = p3 + bs;
    }
}

// ---------------- graph boundaries (graph_id is sorted) ----------------
__global__ void k_starts(const int* __restrict__ gid, int* __restrict__ starts) {
    int g = threadIdx.x;  // 0..255
    int lo = 0, hi = N_NODES;
    while (lo < hi) {
        int mid = (lo + hi) >> 1;
        if (gid[mid] < g) lo = mid + 1; else hi = mid;
    }
    starts[g] = lo;
    if (g == 0) starts[NUM_GRAPHS] = N_NODES;
}

// ---------------- segment softmax pooling + final dot (h16 input) ----------------
__global__ void __launch_bounds__(128) k_pool(
    const unsigned short* __restrict__ h16, const float* __restrict__ a,
    const int* __restrict__ starts, const float* __restrict__ wout,
    const float* __restrict__ bout, float* __restrict__ out) {
    int g = blockIdx.x, j = threadIdx.x;
    int s0 = starts[g], s1 = starts[g + 1];
    __shared__ float red[128];
    __shared__ float exb[128];
    if (s1 <= s0) { if (j == 0) out[g] = bout[0]; return; }
    float m = -3.4e38f;
    for (int i = s0 + j; i < s1; i += 128) m = fmaxf(m, a[i]);
    red[j] = m; __syncthreads();
    for (int s = 64; s > 0; s >>= 1) {
        if (j < s) red[j] = fmaxf(red[j], red[j + s]);
        __syncthreads();
    }
    m = red[0]; __syncthreads();
    float zj = 0.f, ss = 0.f;
    for (int base = s0; base < s1; base += 128) {
        int cnt = min(128, s1 - base);
        float ev = 0.f;
        if (j < cnt) ev = expf(a[base + j] - m);
        exb[j] = ev;
        ss += ev;
        __syncthreads();
        for (int k = 0; k < cnt; k++) {
            __half hv = __builtin_bit_cast(__half, h16[(size_t)(base + k) * HID + j]);
            zj = fmaf(exb[k], __half2float(hv), zj);
        }
        __syncthreads();
    }
    red[j] = ss; __syncthreads();
    for (int s = 64; s > 0; s >>= 1) {
        if (j < s) red[j] += red[j + s];
        __syncthreads();
    }
    ss = red[0]; __syncthreads();
    red[j] = (zj / ss) * wout[j]; __syncthreads();
    for (int s = 64; s > 0; s >>= 1) {
        if (j < s) red[j] += red[j + s];
        __syncthreads();
    }
    if (j == 0) out[g] = red[0] + bout[0];
}

extern "C" void kernel_launch(void* const* d_in, const int* in_sizes, int n_in,
                              void* d_out, int out_size, void* d_ws, size_t ws_size,
                              hipStream_t stream) {
    const float* feat    = (const float*)d_in[0];
    const int*   qrel    = (const int*)d_in[1];
    const int*   src     = (const int*)d_in[2];
    const int*   dst     = (const int*)d_in[3];
    const int*   ety     = (const int*)d_in[4];
    const int*   gid     = (const int*)d_in[5];
    const float* rel_emb = (const float*)d_in[6];
    const float* W_in    = (const float*)d_in[7];
    const float* b_in    = (const float*)d_in[8];
    const float* V       = (const float*)d_in[9];
    const float* comp    = (const float*)d_in[10];
    const float* W_loop  = (const float*)d_in[11];
    const float* b_loop  = (const float*)d_in[12];
    const float* W_attn  = (const float*)d_in[13];
    const float* b_attn  = (const float*)d_in[14];
    const float* w_sc    = (const float*)d_in[15];
    const float* b_sc    = (const float*)d_in[16];
    const float* w_out   = (const float*)d_in[17];
    const float* b_out   = (const float*)d_in[18];
    float* out = (float*)d_out;

    float* ws = (float*)d_ws;
    unsigned short* h16a = (unsigned short*)ws;           // 6.4M ushort
    unsigned short* h16b = h16a + (size_t)N_NODES * HID;  // 6.4M ushort
    unsigned short* er16 = h16b + (size_t)N_NODES * HID;  // 1.6M ushort
    float* af = (float*)(er16 + (size_t)N_NODES * REL_DIM);  // 50000 f32
    int* starts    = (int*)(af + N_NODES);                // 260
    int* row_start = starts + 260;                        // 50004
    int* off       = row_start + 50004;                   // 100352
    int* bsum      = off + OFFN;                          // 392
    int* boff      = bsum + SC2_BLKS;                     // 392
    int* tmp_e     = boff + SC2_BLKS;                     // 800000
    int* edge_p    = tmp_e + 800000;                      // 800000
    unsigned short* Bf = (unsigned short*)(edge_p + 800000);  // 2*36*8*64*8 ushort
    const size_t BF_USHORT = (size_t)NUM_LAYERS * 36 * 8 * 64 * 8;
    unsigned short* Waf = Bf + BF_USHORT;                 // 5*8*64*8 = 20480 ushort
    unsigned short* Gf = Waf + 20480;

    size_t used_floats = (size_t)((float*)Gf - ws);
    size_t total_floats = ws_size / sizeof(float);
    size_t avail = (total_floats > used_floats) ? (total_floats - used_floats) : 0;
    long long NC = (long long)(avail / 512);   // 1024 fp16 per row = 512 floats
    NC = (NC / 64) * 64;
    if (NC > 50048) NC = 50048;
    if (NC < 64) NC = 64;

    // --- preprocessing: bucketed counting sort -> edge_p + row_start ---
    k_bhist<<<PBLK, 256, 0, stream>>>(dst, off);
    k_scan2_a<<<SC2_BLKS, 256, 0, stream>>>(off, bsum);
    k_scan2_b<<<1, 512, 0, stream>>>(bsum, boff);
    k_scan2_c<<<SC2_BLKS, 256, 0, stream>>>(off, boff);
    k_bscatter<<<PBLK, 256, 0, stream>>>(src, dst, ety, off, tmp_e);
    k_bsort<<<NBUCK, 256, 0, stream>>>(off, tmp_e, edge_p, row_start);
    k_bfrag<<<(NUM_LAYERS * 36 * 8 * 64 + 255) / 256, 256, 0, stream>>>(V, W_loop, Bf);
    k_bfragw<<<(5 * 8 * 64 + 255) / 256, 256, 0, stream>>>(W_attn, Waf, 5);
    k_input<<<N_NODES / 16, 128, 0, stream>>>(feat, qrel, rel_emb, W_in, b_in, h16a, er16);

    unsigned short* h16cur = h16a;
    unsigned short* h16next = h16b;
    for (int l = 0; l < NUM_LAYERS; l++) {
        const float* comp_l = comp + (size_t)l * NUM_RELS * NUM_BASES;
        const unsigned short* Bfl = Bf + (size_t)l * 36 * 8 * 64 * 8;
        const float* bl = b_loop + (size_t)l * HID;
        for (int c0 = 0; c0 < N_NODES; c0 += (int)NC) {
            int nc = (int)((N_NODES - c0 < NC) ? (N_NODES - c0) : NC);
            k_mix2<<<(nc + 3) / 4, 256, 0, stream>>>(h16cur, comp_l, row_start, edge_p,
                                                     Gf, c0, nc);
            k_gemm9<<<(nc + 63) / 64, 256, 0, stream>>>(Gf, h16cur, Bfl, bl,
                                                        h16next, c0, nc);
        }
        unsigned short* tmp16 = h16cur; h16cur = h16next; h16next = tmp16;
    }

    k_score2<<<(N_NODES + 63) / 64, 256, 0, stream>>>(h16cur, er16, Waf, b_attn,
                                                      w_sc, b_sc, af);
    k_starts<<<1, 256, 0, stream>>>(gid, starts);
    k_pool<<<NUM_GRAPHS, 128, 0, stream>>>(h16cur, af, starts, w_out, b_out, out);
}

// Round 22
// 280.745 us; speedup vs baseline: 1.3733x; 1.0018x over previous
//
#include <hip/hip_runtime.h>
#include <hip/hip_fp16.h>

#define N_NODES   50000
#define N_EDGES   800000
#define NUM_GRAPHS 256
#define IN_FEAT   64
#define REL_DIM   32
#define HID       128
#define NUM_RELS  32
#define NUM_BASES 8
#define NUM_LAYERS 2

#define NBUCK 196            // dst >> 8
#define PBLK  512            // scatter blocks
#define CHUNK 1563           // ceil(800000/512)
#define OFFN  (NBUCK * PBLK) // 100352
#define SC2_BLKS (OFFN / 256)  // 392

typedef __attribute__((ext_vector_type(8))) _Float16 f16x8;
typedef __attribute__((ext_vector_type(4))) float f32x4;
typedef __attribute__((ext_vector_type(2))) float f32x2;

// async 16B global -> LDS (wave-uniform LDS base + lane*16; per-lane global src)
__device__ __forceinline__ void gld_lds16(void* lds, const void* g) {
    __builtin_amdgcn_global_load_lds(
        (const __attribute__((address_space(1))) unsigned int*)g,
        (__attribute__((address_space(3))) unsigned int*)lds, 16, 0, 0);
}

// ---------------- edge sort phase A: per-(block,bucket) histogram ----------------
__global__ void __launch_bounds__(256) k_bhist(const int* __restrict__ dst,
                                               int* __restrict__ off) {
    __shared__ int hist[NBUCK];
    int t = threadIdx.x;
    if (t < NBUCK) hist[t] = 0;
    __syncthreads();
    int base = blockIdx.x * CHUNK;
    for (int i = t; i < CHUNK; i += 256) {
        int e = base + i;
        if (e < N_EDGES) atomicAdd(&hist[dst[e] >> 8], 1);
    }
    __syncthreads();
    if (t < NBUCK) off[t * PBLK + blockIdx.x] = hist[t];
}

// ---------------- phase B: multi-block exclusive scan of off[OFFN] ----------------
__global__ void __launch_bounds__(256) k_scan2_a(int* __restrict__ off,
                                                 int* __restrict__ bsum) {
    __shared__ int s[256];
    int t = threadIdx.x;
    int idx = blockIdx.x * 256 + t;
    int v = off[idx];
    s[t] = v;
    __syncthreads();
    for (int o = 1; o < 256; o <<= 1) {
        int u = (t >= o) ? s[t - o] : 0;
        __syncthreads();
        s[t] += u;
        __syncthreads();
    }
    off[idx] = s[t] - v;                 // local exclusive
    if (t == 255) bsum[blockIdx.x] = s[255];
}

__global__ void __launch_bounds__(512) k_scan2_b(int* __restrict__ bsum,
                                                 int* __restrict__ boff) {
    __shared__ int s[512];
    int t = threadIdx.x;
    int v = (t < SC2_BLKS) ? bsum[t] : 0;
    s[t] = v;
    __syncthreads();
    for (int o = 1; o < 512; o <<= 1) {
        int u = (t >= o) ? s[t - o] : 0;
        __syncthreads();
        s[t] += u;
        __syncthreads();
    }
    if (t < SC2_BLKS) boff[t] = s[t] - v;   // exclusive
}

__global__ void __launch_bounds__(256) k_scan2_c(int* __restrict__ off,
                                                 const int* __restrict__ boff) {
    int idx = blockIdx.x * 256 + threadIdx.x;
    off[idx] += boff[blockIdx.x];
}

// ---------------- phase C: bucket-scatter (packed (dl<<21)|(src<<5)|ety) ----------------
__global__ void __launch_bounds__(256) k_bscatter(
    const int* __restrict__ src, const int* __restrict__ dst,
    const int* __restrict__ ety, const int* __restrict__ off,
    int* __restrict__ tmp) {
    __shared__ int cur[NBUCK];
    int t = threadIdx.x;
    if (t < NBUCK) cur[t] = off[t * PBLK + blockIdx.x];
    __syncthreads();
    int base = blockIdx.x * CHUNK;
    for (int i = t; i < CHUNK; i += 256) {
        int e = base + i;
        if (e < N_EDGES) {
            int d = dst[e];
            int pos = atomicAdd(&cur[d >> 8], 1);
            tmp[pos] = ((d & 255) << 21) | (src[e] << 5) | ety[e];
        }
    }
}

// ---------------- phase D: per-bucket counting sort; emits row_start + PRESCALED payload ----------------
// edge_p = (src<<13) | ety  -> (edge_p >> 5) == src*256 == byte offset of h16 row
__global__ void __launch_bounds__(256) k_bsort(
    const int* __restrict__ off, const int* __restrict__ tmp,
    int* __restrict__ edge_p, int* __restrict__ row_start) {
    int b = blockIdx.x, t = threadIdx.x;
    int eb = off[b * PBLK];
    int ee = (b == NBUCK - 1) ? N_EDGES : off[(b + 1) * PBLK];
    __shared__ int cnt[256];
    __shared__ int cur[256];
    cnt[t] = 0;
    __syncthreads();
    for (int i = eb + t; i < ee; i += 256)
        atomicAdd(&cnt[(tmp[i] >> 21) & 255], 1);
    __syncthreads();
    int v = cnt[t];
    __shared__ int s[256];
    s[t] = v;
    __syncthreads();
    for (int o = 1; o < 256; o <<= 1) {
        int u = (t >= o) ? s[t - o] : 0;
        __syncthreads();
        s[t] += u;
        __syncthreads();
    }
    int excl = s[t] - v;
    cur[t] = eb + excl;
    int node = b * 256 + t;
    if (node < N_NODES) row_start[node] = eb + excl;
    if (b == NBUCK - 1 && t == 0) row_start[N_NODES] = N_EDGES;
    __syncthreads();
    for (int i = eb + t; i < ee; i += 256) {
        int x = tmp[i];
        int pos = atomicAdd(&cur[(x >> 21) & 255], 1);
        // x & 0x1FFFFF = (src<<5)|ety ; re-encode to (src<<13)|ety
        edge_p[pos] = ((x & 0x1FFFE0) << 8) | (x & 31);
    }
}

// ---------------- input projection (16 nodes/block): h16 = fp16(relu([feat, er] @ W_in + b_in)) ----------------
__global__ void __launch_bounds__(128) k_input(
    const float* __restrict__ feat, const int* __restrict__ qrel,
    const float* __restrict__ rel_emb, const float* __restrict__ Wi,
    const float* __restrict__ bi, unsigned short* __restrict__ h16,
    unsigned short* __restrict__ er16) {
    int n0 = blockIdx.x * 16;
    int j = threadIdx.x;
    int u = j >> 3, q = j & 7;
    __shared__ float xT[96][16];
    {
        const float4* f4 = (const float4*)(feat + (size_t)(n0 + u) * IN_FEAT);
        float4 a = f4[q], b = f4[q + 8];
        xT[4 * q + 0][u] = a.x; xT[4 * q + 1][u] = a.y;
        xT[4 * q + 2][u] = a.z; xT[4 * q + 3][u] = a.w;
        xT[32 + 4 * q + 0][u] = b.x; xT[32 + 4 * q + 1][u] = b.y;
        xT[32 + 4 * q + 2][u] = b.z; xT[32 + 4 * q + 3][u] = b.w;
        int qr = qrel[n0 + u];
        float4 e4 = ((const float4*)(rel_emb + (size_t)qr * REL_DIM))[q];
        xT[64 + 4 * q + 0][u] = e4.x; xT[64 + 4 * q + 1][u] = e4.y;
        xT[64 + 4 * q + 2][u] = e4.z; xT[64 + 4 * q + 3][u] = e4.w;
        __half2 e01 = __floats2half2_rn(e4.x, e4.y);
        __half2 e23 = __floats2half2_rn(e4.z, e4.w);
        *(unsigned*)&er16[(size_t)(n0 + u) * REL_DIM + 4 * q] =
            __builtin_bit_cast(unsigned, e01);
        *(unsigned*)&er16[(size_t)(n0 + u) * REL_DIM + 4 * q + 2] =
            __builtin_bit_cast(unsigned, e23);
    }
    __syncthreads();
    float bj = bi[j];
    float acc[16];
#pragma unroll
    for (int k = 0; k < 16; k++) acc[k] = bj;
    for (int d = 0; d < 96; d++) {
        float w = Wi[d * HID + j];
        float4 x0 = *(const float4*)&xT[d][0];
        float4 x1 = *(const float4*)&xT[d][4];
        float4 x2 = *(const float4*)&xT[d][8];
        float4 x3 = *(const float4*)&xT[d][12];
        acc[0]  = fmaf(x0.x, w, acc[0]);  acc[1]  = fmaf(x0.y, w, acc[1]);
        acc[2]  = fmaf(x0.z, w, acc[2]);  acc[3]  = fmaf(x0.w, w, acc[3]);
        acc[4]  = fmaf(x1.x, w, acc[4]);  acc[5]  = fmaf(x1.y, w, acc[5]);
        acc[6]  = fmaf(x1.z, w, acc[6]);  acc[7]  = fmaf(x1.w, w, acc[7]);
        acc[8]  = fmaf(x2.x, w, acc[8]);  acc[9]  = fmaf(x2.y, w, acc[9]);
        acc[10] = fmaf(x2.z, w, acc[10]); acc[11] = fmaf(x2.w, w, acc[11]);
        acc[12] = fmaf(x3.x, w, acc[12]); acc[13] = fmaf(x3.y, w, acc[13]);
        acc[14] = fmaf(x3.z, w, acc[14]); acc[15] = fmaf(x3.w, w, acc[15]);
    }
#pragma unroll
    for (int k = 0; k < 16; k++) {
        float v = fmaxf(acc[k], 0.f);
        __half hv = __float2half(v);
        h16[(size_t)(n0 + k) * HID + j] = __builtin_bit_cast(unsigned short, hv);
    }
}

// ---------------- per-dst basis-weighted gather (fp16 h), 8-deep, prescaled offsets ----------------
__global__ void __launch_bounds__(256) k_mix2(
    const unsigned short* __restrict__ h16, const float* __restrict__ comp_l,
    const int* __restrict__ row_start, const int* __restrict__ edge_p,
    unsigned short* __restrict__ Gf, int c0, int nc) {
    __shared__ f32x2 cs2[NUM_RELS * NUM_BASES];
    if (threadIdx.x < NUM_RELS * NUM_BASES) {
        float c = comp_l[threadIdx.x];
        cs2[threadIdx.x] = (f32x2){c, c};
    }
    __syncthreads();
    int wave = threadIdx.x >> 6, lane = threadIdx.x & 63;
    int n = c0 + blockIdx.x * 4 + wave;
    if (n >= c0 + nc) return;
    int e0 = row_start[n], e1 = row_start[n + 1];
    const char* hb = (const char*)h16 + lane * 4;   // per-lane base; row byte-off = p>>5
    f32x2 acc[NUM_BASES] = {};
    int e = e0;
    for (; e + 8 <= e1; e += 8) {
        int p0 = edge_p[e],     p1 = edge_p[e + 1], p2 = edge_p[e + 2], p3 = edge_p[e + 3];
        int p4 = edge_p[e + 4], p5 = edge_p[e + 5], p6 = edge_p[e + 6], p7 = edge_p[e + 7];
        unsigned u0 = *(const unsigned*)(hb + (p0 >> 5));
        unsigned u1 = *(const unsigned*)(hb + (p1 >> 5));
        unsigned u2 = *(const unsigned*)(hb + (p2 >> 5));
        unsigned u3 = *(const unsigned*)(hb + (p3 >> 5));
        unsigned u4 = *(const unsigned*)(hb + (p4 >> 5));
        unsigned u5 = *(const unsigned*)(hb + (p5 >> 5));
        unsigned u6 = *(const unsigned*)(hb + (p6 >> 5));
        unsigned u7 = *(const unsigned*)(hb + (p7 >> 5));
        const f32x2* c0p = &cs2[(p0 & 31) * NUM_BASES];
        const f32x2* c1p = &cs2[(p1 & 31) * NUM_BASES];
        const f32x2* c2p = &cs2[(p2 & 31) * NUM_BASES];
        const f32x2* c3p = &cs2[(p3 & 31) * NUM_BASES];
        const f32x2* c4p = &cs2[(p4 & 31) * NUM_BASES];
        const f32x2* c5p = &cs2[(p5 & 31) * NUM_BASES];
        const f32x2* c6p = &cs2[(p6 & 31) * NUM_BASES];
        const f32x2* c7p = &cs2[(p7 & 31) * NUM_BASES];
        float2 t0 = __half22float2(__builtin_bit_cast(__half2, u0));
        float2 t1 = __half22float2(__builtin_bit_cast(__half2, u1));
        float2 t2 = __half22float2(__builtin_bit_cast(__half2, u2));
        float2 t3 = __half22float2(__builtin_bit_cast(__half2, u3));
        float2 t4 = __half22float2(__builtin_bit_cast(__half2, u4));
        float2 t5 = __half22float2(__builtin_bit_cast(__half2, u5));
        float2 t6 = __half22float2(__builtin_bit_cast(__half2, u6));
        float2 t7 = __half22float2(__builtin_bit_cast(__half2, u7));
        f32x2 v0 = {t0.x, t0.y}, v1 = {t1.x, t1.y}, v2 = {t2.x, t2.y}, v3 = {t3.x, t3.y};
        f32x2 v4 = {t4.x, t4.y}, v5 = {t5.x, t5.y}, v6 = {t6.x, t6.y}, v7 = {t7.x, t7.y};
#pragma unroll
        for (int b = 0; b < NUM_BASES; b++) {
            acc[b] += c0p[b] * v0;
            acc[b] += c1p[b] * v1;
            acc[b] += c2p[b] * v2;
            acc[b] += c3p[b] * v3;
            acc[b] += c4p[b] * v4;
            acc[b] += c5p[b] * v5;
            acc[b] += c6p[b] * v6;
            acc[b] += c7p[b] * v7;
        }
    }
    for (; e < e1; e++) {
        int se = edge_p[e];
        const f32x2* cp = &cs2[(se & 31) * NUM_BASES];
        unsigned u = *(const unsigned*)(hb + (se >> 5));
        float2 tv = __half22float2(__builtin_bit_cast(__half2, u));
        f32x2 v = {tv.x, tv.y};
#pragma unroll
        for (int b = 0; b < NUM_BASES; b++) acc[b] += cp[b] * v;
    }
    size_t base = (size_t)(n - c0) * 1024 + 2 * lane;
#pragma unroll
    for (int b = 0; b < NUM_BASES; b++) {
        __half2 g2 = __floats2half2_rn(acc[b][0], acc[b][1]);
        *(unsigned*)&Gf[base + b * 128] = __builtin_bit_cast(unsigned, g2);
    }
}

// ---------------- B fragment table: f16 (hi only) of [Vl ; Wl], MFMA fragment order ----------------
__global__ void k_bfrag(const float* __restrict__ V, const float* __restrict__ W_loop,
                        unsigned short* __restrict__ Bf) {
    int idx = blockIdx.x * 256 + threadIdx.x;
    if (idx >= NUM_LAYERS * 36 * 8 * 64) return;
    int lane = idx & 63;
    int t = (idx >> 6) & 7;
    int s = (idx >> 9) % 36;
    int l = (idx >> 9) / 36;
    int col = t * 16 + (lane & 15);
    int kbase = s * 32 + (lane >> 4) * 8;
    unsigned short* o = Bf + (size_t)idx * 8;
#pragma unroll
    for (int j = 0; j < 8; j++) {
        int k = kbase + j;
        float f = (k < 1024) ? V[((size_t)l * 1024 + k) * HID + col]
                             : W_loop[((size_t)l * HID + (k - 1024)) * HID + col];
        __half hh = __float2half(f);
        o[j] = __builtin_bit_cast(unsigned short, hh);
    }
}

// ---------------- generic frag table for a [S*32][128] f32 matrix (hi f16) ----------------
__global__ void k_bfragw(const float* __restrict__ W, unsigned short* __restrict__ out,
                         int S) {
    int idx = blockIdx.x * 256 + threadIdx.x;
    if (idx >= S * 8 * 64) return;
    int lane = idx & 63;
    int t = (idx >> 6) & 7;
    int s = idx >> 9;
    int col = t * 16 + (lane & 15);
    int kbase = s * 32 + (lane >> 4) * 8;
    unsigned short* o = out + (size_t)idx * 8;
#pragma unroll
    for (int j = 0; j < 8; j++) {
        __half hh = __float2half(W[(size_t)(kbase + j) * HID + col]);
        o[j] = __builtin_bit_cast(unsigned short, hh);
    }
}

// ---------------- f16 MFMA GEMM (BM=64, BK=128, single-B) ----------------
__global__ void __launch_bounds__(256) k_gemm9(
    const unsigned short* __restrict__ Gf, const unsigned short* __restrict__ h16,
    const unsigned short* __restrict__ Bf, const float* __restrict__ bl,
    unsigned short* __restrict__ out16, int c0, int nc) {
    __shared__ unsigned short smem[2][16][512];  // [buf][frag][1KB] = 32KB
    int lane = threadIdx.x & 63;
    int w = threadIdx.x >> 6;
    int rit = lane & 15, kg = lane >> 4;
    int r0 = blockIdx.x * 64;
    int sr0 = r0 + 0 * 16 + rit; if (sr0 >= nc) sr0 = nc - 1;
    int sr1 = r0 + 1 * 16 + rit; if (sr1 >= nc) sr1 = nc - 1;
    int sr2 = r0 + 2 * 16 + rit; if (sr2 >= nc) sr2 = nc - 1;
    int sr3 = r0 + 3 * 16 + rit; if (sr3 >= nc) sr3 = nc - 1;
    int koff = w * 32 + kg * 8;
    const unsigned short* gs0 = Gf + (size_t)sr0 * 1024 + koff;
    const unsigned short* gs1 = Gf + (size_t)sr1 * 1024 + koff;
    const unsigned short* gs2 = Gf + (size_t)sr2 * 1024 + koff;
    const unsigned short* gs3 = Gf + (size_t)sr3 * 1024 + koff;
    const f16x8* bb = (const f16x8*)Bf + (size_t)(2 * w) * 64 + lane;
    f32x4 acc[4][2] = {};

#define STAGE(BUF, STEP) {                                        \
        gld_lds16(&smem[BUF][w * 4 + 0][0], gs0 + (STEP) * 128);  \
        gld_lds16(&smem[BUF][w * 4 + 1][0], gs1 + (STEP) * 128);  \
        gld_lds16(&smem[BUF][w * 4 + 2][0], gs2 + (STEP) * 128);  \
        gld_lds16(&smem[BUF][w * 4 + 3][0], gs3 + (STEP) * 128); }
#define CSTEP(BUF, STEP) _Pragma("unroll")                                   \
    for (int s = 0; s < 4; s++) {                                            \
        const f16x8* bp = bb + (size_t)((STEP) * 4 + s) * 512;               \
        f16x8 bh0 = bp[0], bh1 = bp[64];                                     \
        _Pragma("unroll")                                                    \
        for (int i = 0; i < 4; i++) {                                        \
            f16x8 a = *(const f16x8*)&smem[BUF][s * 4 + i][lane * 8];        \
            acc[i][0] = __builtin_amdgcn_mfma_f32_16x16x32_f16(a, bh0, acc[i][0], 0, 0, 0); \
            acc[i][1] = __builtin_amdgcn_mfma_f32_16x16x32_f16(a, bh1, acc[i][1], 0, 0, 0); \
        }                                                                    \
    }

    STAGE(0, 0);
    for (int t = 0; t < 8; t++) {
        __syncthreads();
        if (t < 7) STAGE((t + 1) & 1, t + 1);
        CSTEP(t & 1, t);
    }
    {
        const unsigned short* hp0 = h16 + (size_t)(c0 + sr0) * HID + kg * 8;
        const unsigned short* hp1 = h16 + (size_t)(c0 + sr1) * HID + kg * 8;
        const unsigned short* hp2 = h16 + (size_t)(c0 + sr2) * HID + kg * 8;
        const unsigned short* hp3 = h16 + (size_t)(c0 + sr3) * HID + kg * 8;
#pragma unroll
        for (int s = 32; s < 36; s++) {
            int o = (s - 32) * 32;
            f16x8 a0 = *(const f16x8*)(hp0 + o);
            f16x8 a1 = *(const f16x8*)(hp1 + o);
            f16x8 a2 = *(const f16x8*)(hp2 + o);
            f16x8 a3 = *(const f16x8*)(hp3 + o);
            const f16x8* bp = bb + (size_t)s * 512;
            f16x8 bh0 = bp[0], bh1 = bp[64];
            acc[0][0] = __builtin_amdgcn_mfma_f32_16x16x32_f16(a0, bh0, acc[0][0], 0, 0, 0);
            acc[0][1] = __builtin_amdgcn_mfma_f32_16x16x32_f16(a0, bh1, acc[0][1], 0, 0, 0);
            acc[1][0] = __builtin_amdgcn_mfma_f32_16x16x32_f16(a1, bh0, acc[1][0], 0, 0, 0);
            acc[1][1] = __builtin_amdgcn_mfma_f32_16x16x32_f16(a1, bh1, acc[1][1], 0, 0, 0);
            acc[2][0] = __builtin_amdgcn_mfma_f32_16x16x32_f16(a2, bh0, acc[2][0], 0, 0, 0);
            acc[2][1] = __builtin_amdgcn_mfma_f32_16x16x32_f16(a2, bh1, acc[2][1], 0, 0, 0);
            acc[3][0] = __builtin_amdgcn_mfma_f32_16x16x32_f16(a3, bh0, acc[3][0], 0, 0, 0);
            acc[3][1] = __builtin_amdgcn_mfma_f32_16x16x32_f16(a3, bh1, acc[3][1], 0, 0, 0);
        }
    }
#undef STAGE
#undef CSTEP
    int col0 = 2 * w * 16 + rit;
    float b0 = bl[col0], b1 = bl[col0 + 16];
#pragma unroll
    for (int i = 0; i < 4; i++) {
        int rq = r0 + i * 16 + kg * 4;
#pragma unroll
        for (int q = 0; q < 4; q++) {
            int row = rq + q;
            if (row < nc) {
                float v0 = fmaxf(acc[i][0][q] + b0, 0.f);
                float v1 = fmaxf(acc[i][1][q] + b1, 0.f);
                size_t o = (size_t)(c0 + row) * HID;
                out16[o + col0] = __builtin_bit_cast(unsigned short, __float2half(v0));
                out16[o + col0 + 16] = __builtin_bit_cast(unsigned short, __float2half(v1));
            }
        }
    }
}

// ---------------- MFMA attention score: a = tanh([h16|er16]@Wa + ba)@wsc + bsc ----------------
__global__ void __launch_bounds__(256) k_score2(
    const unsigned short* __restrict__ h16, const unsigned short* __restrict__ er16,
    const unsigned short* __restrict__ Waf, const float* __restrict__ ba,
    const float* __restrict__ wsc, const float* __restrict__ bsc,
    float* __restrict__ a) {
    int lane = threadIdx.x & 63, w = threadIdx.x >> 6;
    int r0 = blockIdx.x * 64 + w * 16;
    int rit = lane & 15, kg = lane >> 4;
    int row = r0 + rit; if (row >= N_NODES) row = N_NODES - 1;
    const f16x8* bb = (const f16x8*)Waf;
    f32x4 acc[8] = {};
#pragma unroll
    for (int s = 0; s < 5; s++) {
        f16x8 a8;
        if (s < 4) a8 = *(const f16x8*)(h16 + (size_t)row * HID + s * 32 + kg * 8);
        else       a8 = *(const f16x8*)(er16 + (size_t)row * REL_DIM + kg * 8);
#pragma unroll
        for (int t = 0; t < 8; t++)
            acc[t] = __builtin_amdgcn_mfma_f32_16x16x32_f16(
                a8, bb[(size_t)(s * 8 + t) * 64 + lane], acc[t], 0, 0, 0);
    }
    float p0 = 0.f, p1 = 0.f, p2 = 0.f, p3 = 0.f;
#pragma unroll
    for (int t = 0; t < 8; t++) {
        int col = t * 16 + rit;
        float bc = ba[col];
        float ws = wsc[col];
        p0 += tanhf(acc[t][0] + bc) * ws;
        p1 += tanhf(acc[t][1] + bc) * ws;
        p2 += tanhf(acc[t][2] + bc) * ws;
        p3 += tanhf(acc[t][3] + bc) * ws;
    }
#pragma unroll
    for (int m = 1; m < 16; m <<= 1) {
        p0 += __shfl_xor(p0, m, 64);
        p1 += __shfl_xor(p1, m, 64);
        p2 += __shfl_xor(p2, m, 64);
        p3 += __shfl_xor(p3, m, 64);
    }
    if (rit == 0) {
        float bs = bsc[0];
        int rr = r0 + kg * 4;
        if (rr + 0 < N_NODES) a[rr + 0] = p0 + bs;
        if (rr + 1 < N_NODES) a[rr + 1] = p1 + bs;
        if (rr + 2 < N_NODES) a[rr + 2] = p2 + bs;
        if (rr + 3 < N_NODES) a[rr + 3] = p3 + bs;
    }
}

// ---------------- graph boundaries (graph_id is sorted) ----------------
__global__ void k_starts(const int* __restrict__ gid, int* __restrict__ starts) {
    int g = threadIdx.x;  // 0..255
    int lo = 0, hi = N_NODES;
    while (lo < hi) {
        int mid = (lo + hi) >> 1;
        if (gid[mid] < g) lo = mid + 1; else hi = mid;
    }
    starts[g] = lo;
    if (g == 0) starts[NUM_GRAPHS] = N_NODES;
}

// ---------------- segment softmax pooling + final dot (h16 input) ----------------
__global__ void __launch_bounds__(128) k_pool(
    const unsigned short* __restrict__ h16, const float* __restrict__ a,
    const int* __restrict__ starts, const float* __restrict__ wout,
    const float* __restrict__ bout, float* __restrict__ out) {
    int g = blockIdx.x, j = threadIdx.x;
    int s0 = starts[g], s1 = starts[g + 1];
    __shared__ float red[128];
    __shared__ float exb[128];
    if (s1 <= s0) { if (j == 0) out[g] = bout[0]; return; }
    float m = -3.4e38f;
    for (int i = s0 + j; i < s1; i += 128) m = fmaxf(m, a[i]);
    red[j] = m; __syncthreads();
    for (int s = 64; s > 0; s >>= 1) {
        if (j < s) red[j] = fmaxf(red[j], red[j + s]);
        __syncthreads();
    }
    m = red[0]; __syncthreads();
    float zj = 0.f, ss = 0.f;
    for (int base = s0; base < s1; base += 128) {
        int cnt = min(128, s1 - base);
        float ev = 0.f;
        if (j < cnt) ev = expf(a[base + j] - m);
        exb[j] = ev;
        ss += ev;
        __syncthreads();
        for (int k = 0; k < cnt; k++) {
            __half hv = __builtin_bit_cast(__half, h16[(size_t)(base + k) * HID + j]);
            zj = fmaf(exb[k], __half2float(hv), zj);
        }
        __syncthreads();
    }
    red[j] = ss; __syncthreads();
    for (int s = 64; s > 0; s >>= 1) {
        if (j < s) red[j] += red[j + s];
        __syncthreads();
    }
    ss = red[0]; __syncthreads();
    red[j] = (zj / ss) * wout[j]; __syncthreads();
    for (int s = 64; s > 0; s >>= 1) {
        if (j < s) red[j] += red[j + s];
        __syncthreads();
    }
    if (j == 0) out[g] = red[0] + bout[0];
}

extern "C" void kernel_launch(void* const* d_in, const int* in_sizes, int n_in,
                              void* d_out, int out_size, void* d_ws, size_t ws_size,
                              hipStream_t stream) {
    const float* feat    = (const float*)d_in[0];
    const int*   qrel    = (const int*)d_in[1];
    const int*   src     = (const int*)d_in[2];
    const int*   dst     = (const int*)d_in[3];
    const int*   ety     = (const int*)d_in[4];
    const int*   gid     = (const int*)d_in[5];
    const float* rel_emb = (const float*)d_in[6];
    const float* W_in    = (const float*)d_in[7];
    const float* b_in    = (const float*)d_in[8];
    const float* V       = (const float*)d_in[9];
    const float* comp    = (const float*)d_in[10];
    const float* W_loop  = (const float*)d_in[11];
    const float* b_loop  = (const float*)d_in[12];
    const float* W_attn  = (const float*)d_in[13];
    const float* b_attn  = (const float*)d_in[14];
    const float* w_sc    = (const float*)d_in[15];
    const float* b_sc    = (const float*)d_in[16];
    const float* w_out   = (const float*)d_in[17];
    const float* b_out   = (const float*)d_in[18];
    float* out = (float*)d_out;

    float* ws = (float*)d_ws;
    unsigned short* h16a = (unsigned short*)ws;           // 6.4M ushort
    unsigned short* h16b = h16a + (size_t)N_NODES * HID;  // 6.4M ushort
    unsigned short* er16 = h16b + (size_t)N_NODES * HID;  // 1.6M ushort
    float* af = (float*)(er16 + (size_t)N_NODES * REL_DIM);  // 50000 f32
    int* starts    = (int*)(af + N_NODES);                // 260
    int* row_start = starts + 260;                        // 50004
    int* off       = row_start + 50004;                   // 100352
    int* bsum      = off + OFFN;                          // 392
    int* boff      = bsum + SC2_BLKS;                     // 392
    int* tmp_e     = boff + SC2_BLKS;                     // 800000
    int* edge_p    = tmp_e + 800000;                      // 800000
    unsigned short* Bf = (unsigned short*)(edge_p + 800000);  // 2*36*8*64*8 ushort
    const size_t BF_USHORT = (size_t)NUM_LAYERS * 36 * 8 * 64 * 8;
    unsigned short* Waf = Bf + BF_USHORT;                 // 5*8*64*8 = 20480 ushort
    unsigned short* Gf = Waf + 20480;

    size_t used_floats = (size_t)((float*)Gf - ws);
    size_t total_floats = ws_size / sizeof(float);
    size_t avail = (total_floats > used_floats) ? (total_floats - used_floats) : 0;
    long long NC = (long long)(avail / 512);   // 1024 fp16 per row = 512 floats
    NC = (NC / 64) * 64;
    if (NC > 50048) NC = 50048;
    if (NC < 64) NC = 64;

    // --- preprocessing: bucketed counting sort -> edge_p + row_start ---
    k_bhist<<<PBLK, 256, 0, stream>>>(dst, off);
    k_scan2_a<<<SC2_BLKS, 256, 0, stream>>>(off, bsum);
    k_scan2_b<<<1, 512, 0, stream>>>(bsum, boff);
    k_scan2_c<<<SC2_BLKS, 256, 0, stream>>>(off, boff);
    k_bscatter<<<PBLK, 256, 0, stream>>>(src, dst, ety, off, tmp_e);
    k_bsort<<<NBUCK, 256, 0, stream>>>(off, tmp_e, edge_p, row_start);
    k_bfrag<<<(NUM_LAYERS * 36 * 8 * 64 + 255) / 256, 256, 0, stream>>>(V, W_loop, Bf);
    k_bfragw<<<(5 * 8 * 64 + 255) / 256, 256, 0, stream>>>(W_attn, Waf, 5);
    k_input<<<N_NODES / 16, 128, 0, stream>>>(feat, qrel, rel_emb, W_in, b_in, h16a, er16);

    unsigned short* h16cur = h16a;
    unsigned short* h16next = h16b;
    for (int l = 0; l < NUM_LAYERS; l++) {
        const float* comp_l = comp + (size_t)l * NUM_RELS * NUM_BASES;
        const unsigned short* Bfl = Bf + (size_t)l * 36 * 8 * 64 * 8;
        const float* bl = b_loop + (size_t)l * HID;
        for (int c0 = 0; c0 < N_NODES; c0 += (int)NC) {
            int nc = (int)((N_NODES - c0 < NC) ? (N_NODES - c0) : NC);
            k_mix2<<<(nc + 3) / 4, 256, 0, stream>>>(h16cur, comp_l, row_start, edge_p,
                                                     Gf, c0, nc);
            k_gemm9<<<(nc + 63) / 64, 256, 0, stream>>>(Gf, h16cur, Bfl, bl,
                                                        h16next, c0, nc);
        }
        unsigned short* tmp16 = h16cur; h16cur = h16next; h16next = tmp16;
    }

    k_score2<<<(N_NODES + 63) / 64, 256, 0, stream>>>(h16cur, er16, Waf, b_attn,
                                                      w_sc, b_sc, af);
    k_starts<<<1, 256, 0, stream>>>(gid, starts);
    k_pool<<<NUM_GRAPHS, 128, 0, stream>>>(h16cur, af, starts, w_out, b_out, out);
}